// Round 20
// baseline (599.634 us; speedup 1.0000x reference)
//
#include <hip/hip_runtime.h>

#define NN 20000
#define NE 320000
#define NG 64
#define D 128
#define D3 384
#define NRBF 20
#define RBF_ROW 24       // fp32 per rbf row -> 96B, 16B-aligned
#define PI_F 3.14159265358979323846f
#define RCUT 10.0f

typedef unsigned int uint;
typedef unsigned short ushort;
typedef __attribute__((ext_vector_type(8))) short bf16x8;
typedef __attribute__((ext_vector_type(4))) float f32x4;
typedef __attribute__((ext_vector_type(2))) float v2f;

__device__ __forceinline__ float silu_f(float x) {
    return x / (1.0f + __expf(-x));
}
__device__ __forceinline__ float b2f(ushort u) {
    return __uint_as_float(((uint)u) << 16);
}
__device__ __forceinline__ ushort f2b(float f) {
    uint u = __float_as_uint(f);
    u = u + 0x7fffu + ((u >> 16) & 1u);
    return (ushort)(u >> 16);
}
__device__ __forceinline__ float plo(uint u) { return __uint_as_float(u << 16); }
__device__ __forceinline__ float phi_(uint u) { return __uint_as_float(u & 0xffff0000u); }

#define MFMA3(acc, aH, aL, bH, bL)                                          \
    acc = __builtin_amdgcn_mfma_f32_16x16x32_bf16(aL, bH, acc, 0, 0, 0);    \
    acc = __builtin_amdgcn_mfma_f32_16x16x32_bf16(aH, bL, acc, 0, 0, 0);    \
    acc = __builtin_amdgcn_mfma_f32_16x16x32_bf16(aH, bH, acc, 0, 0, 0);

// ---------------------------------------------------------------- mega init
__global__ __launch_bounds__(256) void mega_init(
    float* __restrict__ g, int* __restrict__ deg,
    const float* __restrict__ pw1, const float* __restrict__ pw2,
    ushort* __restrict__ w1th, ushort* __restrict__ w1tl,
    ushort* __restrict__ w2th, ushort* __restrict__ w2tl,
    const float* __restrict__ Uw, const float* __restrict__ Vw,
    const float* __restrict__ uw1, const float* __restrict__ uw2,
    ushort* __restrict__ uwt, ushort* __restrict__ vwt,
    ushort* __restrict__ u1t, ushort* __restrict__ u2t)
{
    int stride = gridDim.x * blockDim.x;
    int idx0 = blockIdx.x * blockDim.x + threadIdx.x;
    for (int i = idx0; i < NG * D; i += stride) g[i] = 0.f;
    for (int i = idx0; i < NN; i += stride) deg[i] = 0;
    for (int i = idx0; i < D * D; i += stride) {
        int j = i >> 7, k = i & 127;
        float x = pw1[k * D + j]; ushort h = f2b(x);
        w1th[i] = h; w1tl[i] = f2b(x - b2f(h));
        float a = Uw[k * D + j]; ushort ha = f2b(a);
        uwt[i] = ha; uwt[D * D + i] = f2b(a - b2f(ha));
        float b = Vw[k * D + j]; ushort hb = f2b(b);
        vwt[i] = hb; vwt[D * D + i] = f2b(b - b2f(hb));
    }
    for (int i = idx0; i < D3 * D; i += stride) {
        int j = i >> 7, k = i & 127;
        float x = pw2[k * D3 + j]; ushort h = f2b(x);
        w2th[i] = h; w2tl[i] = f2b(x - b2f(h));
        float y = uw2[k * D3 + j]; ushort hy = f2b(y);
        u2t[i] = hy; u2t[D3 * D + i] = f2b(y - b2f(hy));
    }
    for (int i = idx0; i < 2 * D * D; i += stride) {
        int j = i >> 8, k = i & 255;
        float x = uw1[k * D + j]; ushort h = f2b(x);
        u1t[i] = h; u1t[2 * D * D + i] = f2b(x - b2f(h));
    }
}

// ---------------------------------------------------------------- CSR count
__global__ __launch_bounds__(256) void csr_count(
    const int* __restrict__ dst, int* __restrict__ deg)
{
    int e = blockIdx.x * blockDim.x + threadIdx.x;
    if (e < NE) atomicAdd(&deg[dst[e]], 1);
}

// ---------------------------------------------------------------- scan (CSR offsets + degree-bucket positions)
__global__ __launch_bounds__(1024) void scan_all(
    const int* __restrict__ deg, int* __restrict__ offs,
    int* __restrict__ cursor, int* __restrict__ bpos)
{
    __shared__ int part[1024];
    __shared__ int bc[64];
    int t = threadIdx.x;
    if (t < 64) bc[t] = 0;
    __syncthreads();
    const int per = (NN + 1023) / 1024;  // 20
    int base = t * per;
    int sum = 0;
    for (int i = 0; i < per; i++) {
        int idx = base + i;
        if (idx < NN) {
            int dg = deg[idx];
            sum += dg;
            int b = dg > 63 ? 63 : dg;
            atomicAdd(&bc[b], 1);
        }
    }
    part[t] = sum;
    __syncthreads();
    for (int off = 1; off < 1024; off <<= 1) {
        int vv = (t >= off) ? part[t - off] : 0;
        __syncthreads();
        part[t] += vv;
        __syncthreads();
    }
    int run = part[t] - sum;
    for (int i = 0; i < per; i++) {
        int idx = base + i;
        if (idx < NN) {
            offs[idx] = run;
            cursor[idx] = run;
            run += deg[idx];
        }
    }
    if (t == 1023) offs[NN] = run;
    __syncthreads();
    if (t == 0) {
        int r2 = 0;
        for (int b = 63; b >= 0; b--) { bpos[b] = r2; r2 += bc[b]; }  // descending degree
    }
}

// ---------------------------------------------------------------- geometry + CSR scatter
__global__ __launch_bounds__(256) void geom_scatter(
    const float* __restrict__ evec, const int* __restrict__ dst,
    const int* __restrict__ srcv, const int* __restrict__ atype,
    int* __restrict__ cursor,
    float* __restrict__ rbf, float4* __restrict__ geo,
    int* __restrict__ src_csr, int* __restrict__ styp_csr,
    const int* __restrict__ deg, int* __restrict__ bpos, int* __restrict__ perm)
{
    int e = blockIdx.x * blockDim.x + threadIdx.x;
    if (e < NE) {
        int p = atomicAdd(&cursor[dst[e]], 1);
        float x = evec[e * 3 + 0], y = evec[e * 3 + 1], z = evec[e * 3 + 2];
        float r = sqrtf(x * x + y * y + z * z);
        float inv = 1.0f / r;
        float f = (r < RCUT) ? 0.5f * (cosf(PI_F * r / RCUT) + 1.0f) : 0.0f;
        float4 gg;
        gg.x = x * inv; gg.y = y * inv; gg.z = z * inv; gg.w = f;
        geo[p] = gg;
        int sn = srcv[e];
        src_csr[p] = sn;
        styp_csr[p] = atype[sn];
        float base = PI_F * r / RCUT;
        float sf = inv * f;
        #pragma unroll
        for (int k = 0; k < NRBF; k++) {
            rbf[(size_t)p * RBF_ROW + k] = sinf((float)(k + 1) * base) * sf;
        }
    }
    if (e < NN) {
        int b = deg[e]; if (b > 63) b = 63;
        int p = atomicAdd(&bpos[b], 1);
        perm[p] = e;
    }
}

// ---------------------------------------------------------------- phi table (round 0)
__global__ __launch_bounds__(128) void phi10(
    const float* __restrict__ emb,
    const float* __restrict__ w1, const float* __restrict__ b1,
    const float* __restrict__ w2, const float* __restrict__ b2,
    uint* __restrict__ ptab)
{
    __shared__ float el[D];
    __shared__ float hl[D];
    int t = blockIdx.x, j = threadIdx.x;
    el[j] = emb[t * D + j];
    __syncthreads();
    float acc = b1[j];
    for (int k = 0; k < D; k++) acc += el[k] * w1[k * D + j];
    hl[j] = silu_f(acc);
    __syncthreads();
    float a1 = b2[D + j], a2 = b2[2 * D + j];
    for (int k = 0; k < D; k++) {
        float h = hl[k];
        a1 += h * w2[k * D3 + D + j];
        a2 += h * w2[k * D3 + 2 * D + j];
    }
    ptab[t * D + j] = (uint)f2b(a1) | ((uint)f2b(a2) << 16);
}

// ---------------------------------------------------------------- node gather round 0 (v=0; CSR-sequential)
// waves_per_eu(6,6): v2f weight layout is only ~40 VGPR (count=52 total at R18),
// so a 6-wave/SIMD budget (~85 VGPR cap) has headroom. (4,4) was required only
// for the old 60-scalar-array layout (R4/R9 spills).
__global__ __launch_bounds__(512)
__attribute__((amdgpu_waves_per_eu(6, 6)))
void node_gather_r0(
    const int* __restrict__ offs,
    const int* __restrict__ perm, const int* __restrict__ styp_csr,
    const int* __restrict__ atype, const float* __restrict__ emb,
    const uint* __restrict__ ptab,
    const float* __restrict__ rbf, const float4* __restrict__ geo,
    const float* __restrict__ filt_w, const float* __restrict__ filt_b,
    float* __restrict__ s_new, float* __restrict__ v_new)
{
    int wave = threadIdx.x >> 6;
    int lane = threadIdx.x & 63;
    int widx = blockIdx.x * 4 + (wave >> 1);
    if (widx >= NN) return;
    int node = __builtin_amdgcn_readfirstlane(perm[widx]);
    int half = wave & 1;
    int d = half * 64 + lane;

    v2f wr1v[10], wr2v[10];
    #pragma unroll
    for (int m = 0; m < 10; m++) {
        wr1v[m] = (v2f){filt_w[(2 * m) * D3 + D + d],     filt_w[(2 * m + 1) * D3 + D + d]};
        wr2v[m] = (v2f){filt_w[(2 * m) * D3 + 2 * D + d], filt_w[(2 * m + 1) * D3 + 2 * D + d]};
    }
    float fb1 = filt_b[D + d], fb2 = filt_b[2 * D + d];
    int e0 = __builtin_amdgcn_readfirstlane(offs[node]);
    int e1 = __builtin_amdgcn_readfirstlane(offs[node + 1]);

    float acc_s = 0.f, av0 = 0.f, av1 = 0.f, av2 = 0.f;

    for (int i = e0; i < e1; i += 2) {
        bool hb = (i + 1 < e1);
        int ib = hb ? i + 1 : i;
        float mb = hb ? 1.0f : 0.0f;
        int ta = __builtin_amdgcn_readfirstlane(styp_csr[i]);
        int tb = __builtin_amdgcn_readfirstlane(styp_csr[ib]);
        float4 ga = geo[i];
        float4 gb = geo[ib];
        const float* rpa = rbf + (size_t)i * RBF_ROW;
        const float* rpb = rbf + (size_t)ib * RBF_ROW;
        uint pka = ptab[ta * D + d];
        uint pkb = ptab[tb * D + d];

        v2f Wa1v = {0.f, 0.f}, Wa2v = {0.f, 0.f};
        v2f Wb1v = {0.f, 0.f}, Wb2v = {0.f, 0.f};
        #pragma unroll
        for (int m = 0; m < 10; m++) {
            float2 ra2 = *(const float2*)(rpa + 2 * m);
            float2 rb2 = *(const float2*)(rpb + 2 * m);
            v2f rav = {ra2.x, ra2.y};
            v2f rbv = {rb2.x, rb2.y};
            Wa1v += rav * wr1v[m]; Wa2v += rav * wr2v[m];
            Wb1v += rbv * wr1v[m]; Wb2v += rbv * wr2v[m];
        }
        float Wa1 = Wa1v.x + Wa1v.y + ga.w * fb1;
        float Wa2 = Wa2v.x + Wa2v.y + ga.w * fb2;
        float Wb1 = Wb1v.x + Wb1v.y + gb.w * fb1;
        float Wb2 = Wb2v.x + Wb2v.y + gb.w * fb2;

        float pa1 = plo(pka), pa2 = phi_(pka);
        float pb1 = plo(pkb), pb2 = phi_(pkb);

        float m2a = pa1 * Wa1, m3a = pa2 * Wa2;
        float m2b = pb1 * Wb1 * mb, m3b = pb2 * Wb2 * mb;
        acc_s += m2a + m2b;
        av0 += ga.x * m3a + gb.x * m3b;
        av1 += ga.y * m3a + gb.y * m3b;
        av2 += ga.z * m3a + gb.z * m3b;
    }

    int tn = __builtin_amdgcn_readfirstlane(atype[node]);
    s_new[node * D + d] = emb[tn * D + d] + acc_s;
    v_new[(node * 3 + 0) * D + d] = av0;
    v_new[(node * 3 + 1) * D + d] = av1;
    v_new[(node * 3 + 2) * D + d] = av2;
}

// ---------------------------------------------------------------- node gather (round 1; CSR-sequential)
__global__ __launch_bounds__(512)
__attribute__((amdgpu_waves_per_eu(6, 6)))
void node_gather(
    const int* __restrict__ offs,
    const int* __restrict__ perm, const int* __restrict__ src_csr,
    const ushort* __restrict__ pv,
    const float* __restrict__ s_old, const float* __restrict__ v_old,
    const float* __restrict__ rbf, const float4* __restrict__ geo,
    const float* __restrict__ filt_w, const float* __restrict__ filt_b,
    float* __restrict__ s_new, float* __restrict__ v_new)
{
    int wave = threadIdx.x >> 6;
    int lane = threadIdx.x & 63;
    int widx = blockIdx.x * 4 + (wave >> 1);
    if (widx >= NN) return;
    int node = __builtin_amdgcn_readfirstlane(perm[widx]);
    int half = wave & 1;
    int d = half * 64 + lane;

    v2f wr0v[10], wr1v[10], wr2v[10];
    #pragma unroll
    for (int m = 0; m < 10; m++) {
        wr0v[m] = (v2f){filt_w[(2 * m) * D3 + d],         filt_w[(2 * m + 1) * D3 + d]};
        wr1v[m] = (v2f){filt_w[(2 * m) * D3 + D + d],     filt_w[(2 * m + 1) * D3 + D + d]};
        wr2v[m] = (v2f){filt_w[(2 * m) * D3 + 2 * D + d], filt_w[(2 * m + 1) * D3 + 2 * D + d]};
    }
    float fb0 = filt_b[d], fb1 = filt_b[D + d], fb2 = filt_b[2 * D + d];
    int e0 = __builtin_amdgcn_readfirstlane(offs[node]);
    int e1 = __builtin_amdgcn_readfirstlane(offs[node + 1]);

    float acc_s = 0.f, av0 = 0.f, av1 = 0.f, av2 = 0.f;
    size_t doff = (size_t)d * 6;

    for (int i = e0; i < e1; i += 2) {
        bool hb = (i + 1 < e1);
        int ib = hb ? i + 1 : i;
        float mb = hb ? 1.0f : 0.0f;
        int sa = __builtin_amdgcn_readfirstlane(src_csr[i]);
        int sb = __builtin_amdgcn_readfirstlane(src_csr[ib]);
        float4 ga = geo[i];
        float4 gb = geo[ib];
        const float* rpa = rbf + (size_t)i * RBF_ROW;
        const float* rpb = rbf + (size_t)ib * RBF_ROW;
        uint3 pka = *(const uint3*)(pv + (size_t)sa * 768 + doff);
        uint3 pkb = *(const uint3*)(pv + (size_t)sb * 768 + doff);

        v2f Wa0v = {0.f, 0.f}, Wa1v = {0.f, 0.f}, Wa2v = {0.f, 0.f};
        v2f Wb0v = {0.f, 0.f}, Wb1v = {0.f, 0.f}, Wb2v = {0.f, 0.f};
        #pragma unroll
        for (int m = 0; m < 10; m++) {
            float2 ra2 = *(const float2*)(rpa + 2 * m);
            float2 rb2 = *(const float2*)(rpb + 2 * m);
            v2f rav = {ra2.x, ra2.y};
            v2f rbv = {rb2.x, rb2.y};
            Wa0v += rav * wr0v[m]; Wa1v += rav * wr1v[m]; Wa2v += rav * wr2v[m];
            Wb0v += rbv * wr0v[m]; Wb1v += rbv * wr1v[m]; Wb2v += rbv * wr2v[m];
        }
        float Wa0 = Wa0v.x + Wa0v.y + ga.w * fb0;
        float Wa1 = Wa1v.x + Wa1v.y + ga.w * fb1;
        float Wa2 = Wa2v.x + Wa2v.y + ga.w * fb2;
        float Wb0 = Wb0v.x + Wb0v.y + gb.w * fb0;
        float Wb1 = Wb1v.x + Wb1v.y + gb.w * fb1;
        float Wb2 = Wb2v.x + Wb2v.y + gb.w * fb2;

        float pa0 = plo(pka.x), pa1 = phi_(pka.x), pa2 = plo(pka.y);
        float va0 = phi_(pka.y), va1 = plo(pka.z), va2 = phi_(pka.z);
        float pb0 = plo(pkb.x), pb1 = phi_(pkb.x), pb2 = plo(pkb.y);
        float vb0 = phi_(pkb.y), vb1 = plo(pkb.z), vb2 = phi_(pkb.z);

        float m1a = pa0 * Wa0, m2a = pa1 * Wa1, m3a = pa2 * Wa2;
        float m1b = pb0 * Wb0 * mb, m2b = pb1 * Wb1 * mb, m3b = pb2 * Wb2 * mb;
        acc_s += m2a + m2b;
        av0 += va0 * m1a + ga.x * m3a + vb0 * m1b + gb.x * m3b;
        av1 += va1 * m1a + ga.y * m3a + vb1 * m1b + gb.y * m3b;
        av2 += va2 * m1a + ga.z * m3a + vb2 * m1b + gb.z * m3b;
    }

    s_new[node * D + d] = s_old[node * D + d] + acc_s;
    v_new[(node * 3 + 0) * D + d] = v_old[(node * 3 + 0) * D + d] + av0;
    v_new[(node * 3 + 1) * D + d] = v_old[(node * 3 + 1) * D + d] + av1;
    v_new[(node * 3 + 2) * D + d] = v_old[(node * 3 + 2) * D + d] + av2;
}

// ---------------------------------------------------------------- fused update via MFMA bf16x3 (R18 verified)
template<bool FUSE>
__global__ __launch_bounds__(512) void node_vupd_mfma(
    float* __restrict__ s, float* __restrict__ v, ushort* __restrict__ pv,
    const int* __restrict__ gi, float* __restrict__ g,
    const ushort* __restrict__ uwt, const ushort* __restrict__ vwt,
    const ushort* __restrict__ u1t, const ushort* __restrict__ u2t,
    const float* __restrict__ ub1, const float* __restrict__ ub2,
    const ushort* __restrict__ w1th, const ushort* __restrict__ w1tl,
    const float* __restrict__ pb1,
    const ushort* __restrict__ w2th, const ushort* __restrict__ w2tl,
    const float* __restrict__ pb2)
{
    constexpr int U_BYTES = FUSE ? 13056 : 0;        // [48][136] bf16 (FUSE only)
    constexpr int UV_OFF  = U_BYTES;
    constexpr int B_OFF   = UV_OFF + 8448;           // UV: [16][132] f32
    constexpr int SMEM_SZ = B_OFF + 26112;           // region B (a/x/h or a_out[16][396])
    __shared__ __align__(16) char smem[SMEM_SZ];
    ushort* U_lds  = (ushort*)(smem);
    float*  UV_lds = (float*)(smem + UV_OFF);
    ushort* a_hi   = (ushort*)(smem + B_OFF);        // [48][136]
    ushort* a_lo   = a_hi + 48 * 136;
    ushort* x_hi   = (ushort*)(smem + B_OFF);        // [16][264]
    ushort* x_lo   = x_hi + 16 * 264;
    ushort* h_hi   = x_lo + 16 * 264;                // [16][136]
    ushort* h_lo   = h_hi + 16 * 136;
    float*  a_out  = (float*)(smem + B_OFF);         // [16][396] padded

    int tid = threadIdx.x;
    int wave = tid >> 6, lane = tid & 63;
    int arow = lane & 15, kg = lane >> 4;
    int n0 = blockIdx.x * 16;
    int jw = wave * 16 + arow;                       // this wave's j column

    // ---- phase 1: stage v (bf16 hi/lo)
    #pragma unroll
    for (int it = 0; it < 3; it++) {
        int f4 = it * 512 + tid;
        int row = f4 >> 5;
        int c4 = (f4 & 31) * 4;
        int i = row >> 4, n = row & 15;
        float4 vv = *(const float4*)&v[((size_t)(n0 + n) * 3 + i) * D + c4];
        ushort h0 = f2b(vv.x), h1 = f2b(vv.y), h2 = f2b(vv.z), h3 = f2b(vv.w);
        ushort l0 = f2b(vv.x - b2f(h0)), l1 = f2b(vv.y - b2f(h1));
        ushort l2 = f2b(vv.z - b2f(h2)), l3 = f2b(vv.w - b2f(h3));
        uint2 ph; ph.x = (uint)h0 | ((uint)h1 << 16); ph.y = (uint)h2 | ((uint)h3 << 16);
        uint2 pl; pl.x = (uint)l0 | ((uint)l1 << 16); pl.y = (uint)l2 | ((uint)l3 << 16);
        *(uint2*)&a_hi[row * 136 + c4] = ph;
        *(uint2*)&a_lo[row * 136 + c4] = pl;
    }
    __syncthreads();

    // ---- phase 2: U = v@Uw, Vp = v@Vw (one j-tile per wave)
    f32x4 accU[3], accVp[3];
    #pragma unroll
    for (int i = 0; i < 3; i++) {
        accU[i] = (f32x4){0.f, 0.f, 0.f, 0.f};
        accVp[i] = (f32x4){0.f, 0.f, 0.f, 0.f};
    }
    #pragma unroll
    for (int i = 0; i < 3; i++) {
        #pragma unroll
        for (int t = 0; t < 4; t++) {
            bf16x8 aH = *(const bf16x8*)&a_hi[(i * 16 + arow) * 136 + t * 32 + kg * 8];
            bf16x8 aL = *(const bf16x8*)&a_lo[(i * 16 + arow) * 136 + t * 32 + kg * 8];
            bf16x8 bH = *(const bf16x8*)&uwt[(size_t)jw * 128 + t * 32 + kg * 8];
            bf16x8 bL = *(const bf16x8*)&uwt[(size_t)D * D + (size_t)jw * 128 + t * 32 + kg * 8];
            MFMA3(accU[i], aH, aL, bH, bL)
            bf16x8 cH = *(const bf16x8*)&vwt[(size_t)jw * 128 + t * 32 + kg * 8];
            bf16x8 cL = *(const bf16x8*)&vwt[(size_t)D * D + (size_t)jw * 128 + t * 32 + kg * 8];
            MFMA3(accVp[i], aH, aL, cH, cL)
        }
    }
    __syncthreads();   // a reads done; region B reusable as x

    // ---- phase 3: U->LDS (FUSE), UV->LDS, Vn->x; stage s->x[:,128+]
    #pragma unroll
    for (int r = 0; r < 4; r++) {
        int n = kg * 4 + r;
        if (FUSE) {
            #pragma unroll
            for (int i = 0; i < 3; i++)
                U_lds[(i * 16 + n) * 136 + jw] = f2b(accU[i][r]);
        }
        float uv = accU[0][r] * accVp[0][r]
                 + accU[1][r] * accVp[1][r]
                 + accU[2][r] * accVp[2][r];
        float nn = accVp[0][r] * accVp[0][r]
                 + accVp[1][r] * accVp[1][r]
                 + accVp[2][r] * accVp[2][r];
        UV_lds[n * 132 + jw] = uv;
        float vn = sqrtf(nn);
        ushort hh = f2b(vn);
        x_hi[n * 264 + jw] = hh;
        x_lo[n * 264 + jw] = f2b(vn - b2f(hh));
    }
    #pragma unroll
    for (int it = 0; it < 4; it++) {
        int t8 = it * 512 + tid;
        int n = t8 >> 7, j = t8 & 127;
        float sv = s[(size_t)(n0 + n) * D + j];
        ushort hh = f2b(sv);
        x_hi[n * 264 + 128 + j] = hh;
        x_lo[n * 264 + 128 + j] = f2b(sv - b2f(hh));
    }
    __syncthreads();

    // ---- phase 4: layer 1 (K=256) -> h
    {
        f32x4 acc1 = (f32x4){0.f, 0.f, 0.f, 0.f};
        #pragma unroll
        for (int t = 0; t < 8; t++) {
            bf16x8 aH = *(const bf16x8*)&x_hi[arow * 264 + t * 32 + kg * 8];
            bf16x8 aL = *(const bf16x8*)&x_lo[arow * 264 + t * 32 + kg * 8];
            bf16x8 bH = *(const bf16x8*)&u1t[(size_t)jw * 256 + t * 32 + kg * 8];
            bf16x8 bL = *(const bf16x8*)&u1t[(size_t)2 * D * D + (size_t)jw * 256 + t * 32 + kg * 8];
            MFMA3(acc1, aH, aL, bH, bL)
        }
        float bias = ub1[jw];
        #pragma unroll
        for (int r = 0; r < 4; r++) {
            int n = kg * 4 + r;
            float hv = silu_f(acc1[r] + bias);
            ushort hh = f2b(hv);
            h_hi[n * 136 + jw] = hh;
            h_lo[n * 136 + jw] = f2b(hv - b2f(hh));
        }
    }
    __syncthreads();

    // ---- phase 5: layer 2 (N=384, 3 tiles per wave) -> a_out
    f32x4 acc2[3];
    #pragma unroll
    for (int q = 0; q < 3; q++) acc2[q] = (f32x4){0.f, 0.f, 0.f, 0.f};
    #pragma unroll
    for (int t = 0; t < 4; t++) {
        bf16x8 aH = *(const bf16x8*)&h_hi[arow * 136 + t * 32 + kg * 8];
        bf16x8 aL = *(const bf16x8*)&h_lo[arow * 136 + t * 32 + kg * 8];
        #pragma unroll
        for (int q = 0; q < 3; q++) {
            int j = (wave * 3 + q) * 16 + arow;
            bf16x8 bH = *(const bf16x8*)&u2t[(size_t)j * 128 + t * 32 + kg * 8];
            bf16x8 bL = *(const bf16x8*)&u2t[(size_t)D3 * D + (size_t)j * 128 + t * 32 + kg * 8];
            MFMA3(acc2[q], aH, aL, bH, bL)
        }
    }
    __syncthreads();   // x/h reads done; a_out may overwrite
    #pragma unroll
    for (int q = 0; q < 3; q++) {
        int j = (wave * 3 + q) * 16 + arow;
        float bias = ub2[j];
        #pragma unroll
        for (int r = 0; r < 4; r++)
            a_out[(kg * 4 + r) * 396 + j] = acc2[q][r] + bias;
    }
    __syncthreads();

    // ---- epilogue (coalesced)
    float snew_reg[4];
    #pragma unroll
    for (int it = 0; it < 4; it++) {
        int t8 = it * 512 + tid;
        int n = t8 >> 7, j = t8 & 127;
        float a1 = a_out[n * 396 + 128 + j];
        float a2 = a_out[n * 396 + 256 + j];
        size_t sidx = (size_t)(n0 + n) * D + j;
        float snew = s[sidx] + a2 + UV_lds[n * 132 + j] * a1;
        if (FUSE) {
            float a0 = a_out[n * 396 + j];
            s[sidx] = snew;
            snew_reg[it] = snew;
            ushort* pvp = pv + ((size_t)(n0 + n) * 128 + j) * 6;
            #pragma unroll
            for (int i = 0; i < 3; i++) {
                size_t idx = ((size_t)(n0 + n) * 3 + i) * D + j;
                float vf = v[idx] + b2f(U_lds[(i * 16 + n) * 136 + j]) * a0;
                v[idx] = vf;
                pvp[3 + i] = f2b(vf);
            }
        } else {
            int gn = gi[n0 + n];
            atomicAdd(&g[(size_t)gn * D + j], snew);
        }
    }

    if (!FUSE) return;

    // ---- fused phi for next round: pv[slot 0..2] = phi(s_new)
    __syncthreads();
    #pragma unroll
    for (int it = 0; it < 4; it++) {
        int t8 = it * 512 + tid;
        int n = t8 >> 7, j = t8 & 127;
        float sv = snew_reg[it];
        ushort hh = f2b(sv);
        x_hi[n * 264 + j] = hh;
        x_lo[n * 264 + j] = f2b(sv - b2f(hh));
    }
    __syncthreads();

    {
        f32x4 accp = (f32x4){0.f, 0.f, 0.f, 0.f};
        #pragma unroll
        for (int t = 0; t < 4; t++) {
            bf16x8 aH = *(const bf16x8*)&x_hi[arow * 264 + t * 32 + kg * 8];
            bf16x8 aL = *(const bf16x8*)&x_lo[arow * 264 + t * 32 + kg * 8];
            bf16x8 bH = *(const bf16x8*)&w1th[(size_t)jw * 128 + t * 32 + kg * 8];
            bf16x8 bL = *(const bf16x8*)&w1tl[(size_t)jw * 128 + t * 32 + kg * 8];
            MFMA3(accp, aH, aL, bH, bL)
        }
        __syncthreads();
        float bias = pb1[jw];
        #pragma unroll
        for (int r = 0; r < 4; r++) {
            int n = kg * 4 + r;
            float hv = silu_f(accp[r] + bias);
            ushort hh = f2b(hv);
            h_hi[n * 136 + jw] = hh;
            h_lo[n * 136 + jw] = f2b(hv - b2f(hh));
        }
    }
    __syncthreads();

    {
        f32x4 accq[3];
        #pragma unroll
        for (int q = 0; q < 3; q++) accq[q] = (f32x4){0.f, 0.f, 0.f, 0.f};
        #pragma unroll
        for (int t = 0; t < 4; t++) {
            bf16x8 aH = *(const bf16x8*)&h_hi[arow * 136 + t * 32 + kg * 8];
            bf16x8 aL = *(const bf16x8*)&h_lo[arow * 136 + t * 32 + kg * 8];
            #pragma unroll
            for (int q = 0; q < 3; q++) {
                int j = (wave * 3 + q) * 16 + arow;
                bf16x8 bH = *(const bf16x8*)&w2th[(size_t)j * 128 + t * 32 + kg * 8];
                bf16x8 bL = *(const bf16x8*)&w2tl[(size_t)j * 128 + t * 32 + kg * 8];
                MFMA3(accq[q], aH, aL, bH, bL)
            }
        }
        #pragma unroll
        for (int q = 0; q < 3; q++) {
            int j = (wave * 3 + q) * 16 + arow;
            float bias = pb2[j];
            int seg = j >> 7;
            int ch  = j & 127;
            #pragma unroll
            for (int r = 0; r < 4; r++) {
                pv[((size_t)(n0 + kg * 4 + r) * 128 + ch) * 6 + seg] = f2b(accq[q][r] + bias);
            }
        }
    }
}

// ---------------------------------------------------------------- readout
__global__ __launch_bounds__(128) void out_mlp(
    const float* __restrict__ g,
    const float* __restrict__ w1, const float* __restrict__ b1,
    const float* __restrict__ w2, const float* __restrict__ b2,
    float* __restrict__ out)
{
    __shared__ float gl[D];
    __shared__ float red[2];
    int j = threadIdx.x;
    int gr = blockIdx.x;
    gl[j] = g[gr * D + j];
    __syncthreads();
    float acc = b1[j];
    for (int k = 0; k < D; k++) acc += gl[k] * w1[k * D + j];
    float h = silu_f(acc) * w2[j];
    #pragma unroll
    for (int off = 32; off >= 1; off >>= 1) h += __shfl_down(h, off);
    if ((j & 63) == 0) red[j >> 6] = h;
    __syncthreads();
    if (j == 0) out[gr] = red[0] + red[1] + b2[0];
}

// ================================================================ launch
extern "C" void kernel_launch(void* const* d_in, const int* in_sizes, int n_in,
                              void* d_out, int out_size, void* d_ws, size_t ws_size,
                              hipStream_t stream)
{
    const int*   edge_src   = (const int*)  d_in[0];
    const int*   edge_dst   = (const int*)  d_in[1];
    const float* edge_vec   = (const float*)d_in[2];
    const int*   atom_types = (const int*)  d_in[3];
    const int*   node_gi    = (const int*)  d_in[4];
    const float* embedding  = (const float*)d_in[5];
    const float* phi_w1     = (const float*)d_in[6];
    const float* phi_b1     = (const float*)d_in[7];
    const float* phi_w2     = (const float*)d_in[8];
    const float* phi_b2     = (const float*)d_in[9];
    const float* filt_w     = (const float*)d_in[10];
    const float* filt_b     = (const float*)d_in[11];
    const float* upd_w1     = (const float*)d_in[12];
    const float* upd_b1     = (const float*)d_in[13];
    const float* upd_w2     = (const float*)d_in[14];
    const float* upd_b2     = (const float*)d_in[15];
    const float* U_w        = (const float*)d_in[16];
    const float* V_w        = (const float*)d_in[17];
    const float* out_w1     = (const float*)d_in[18];
    const float* out_b1     = (const float*)d_in[19];
    const float* out_w2     = (const float*)d_in[20];
    const float* out_b2     = (const float*)d_in[21];

    float* ws = (float*)d_ws;
    size_t o = 0;
    float* s_a   = ws + o; o += (size_t)NN * D;
    float* s_b   = ws + o; o += (size_t)NN * D;
    float* v_a   = ws + o; o += (size_t)NN * 3 * D;
    float* v_b   = ws + o; o += (size_t)NN * 3 * D;
    float* pv_f  = ws + o; o += (size_t)NN * 384;             // pv: [n][128][6] bf16
    float* rbf_f = ws + o; o += (size_t)NE * RBF_ROW;         // fp32, CSR order
    float* geo   = ws + o; o += (size_t)NE * 4;               // CSR order
    float* g     = ws + o; o += (size_t)NG * D;
    float* w1t_f = ws + o; o += (size_t)D * D;                // phi w1 hi+lo
    float* w2t_f = ws + o; o += (size_t)D3 * D;               // phi w2 hi+lo
    float* uwt_f = ws + o; o += (size_t)D * D;                // Uw^T hi+lo
    float* vwt_f = ws + o; o += (size_t)D * D;                // Vw^T hi+lo
    float* u1t_f = ws + o; o += (size_t)2 * D * D;            // upd_w1^T hi+lo
    float* u2t_f = ws + o; o += (size_t)D3 * D;               // upd_w2^T hi+lo
    float* ptab_f= ws + o; o += (size_t)10 * D;               // round-0 phi table
    int* deg     = (int*)(ws + o); o += NN;
    int* offs    = (int*)(ws + o); o += NN + 1;
    int* cursor  = (int*)(ws + o); o += NN;
    int* perm    = (int*)(ws + o); o += NN;
    int* bpos    = (int*)(ws + o); o += 64;
    int* src_csr = (int*)(ws + o); o += NE;
    int* styp_csr= (int*)(ws + o); o += NE;

    ushort* pv    = (ushort*)pv_f;
    ushort* w1th  = (ushort*)w1t_f;
    ushort* w1tl  = w1th + (size_t)D * D;
    ushort* w2th  = (ushort*)w2t_f;
    ushort* w2tl  = w2th + (size_t)D3 * D;
    ushort* uwt   = (ushort*)uwt_f;
    ushort* vwt   = (ushort*)vwt_f;
    ushort* u1t   = (ushort*)u1t_f;
    ushort* u2t   = (ushort*)u2t_f;
    uint*   ptab  = (uint*)ptab_f;

    mega_init<<<512, 256, 0, stream>>>(g, deg, phi_w1, phi_w2,
                                       w1th, w1tl, w2th, w2tl,
                                       U_w, V_w, upd_w1, upd_w2,
                                       uwt, vwt, u1t, u2t);
    csr_count<<<(NE + 255) / 256, 256, 0, stream>>>(edge_dst, deg);
    scan_all<<<1, 1024, 0, stream>>>(deg, offs, cursor, bpos);
    geom_scatter<<<(NE + 255) / 256, 256, 0, stream>>>(edge_vec, edge_dst, edge_src,
                                                       atom_types, cursor,
                                                       rbf_f, (float4*)geo,
                                                       src_csr, styp_csr,
                                                       deg, bpos, perm);
    phi10<<<10, 128, 0, stream>>>(embedding, phi_w1, phi_b1, phi_w2, phi_b2, ptab);

    // round 0 (v = 0 specialization)
    node_gather_r0<<<NN / 4, 512, 0, stream>>>(offs, perm, styp_csr,
                                               atom_types, embedding, ptab,
                                               rbf_f, (const float4*)geo,
                                               filt_w, filt_b, s_b, v_b);
    node_vupd_mfma<true><<<NN / 16, 512, 0, stream>>>(s_b, v_b, pv, node_gi, g,
                                                      uwt, vwt, u1t, u2t,
                                                      upd_b1, upd_b2,
                                                      w1th, w1tl, phi_b1,
                                                      w2th, w2tl, phi_b2);
    // round 1
    node_gather<<<NN / 4, 512, 0, stream>>>(offs, perm, src_csr, pv,
                                            s_b, v_b, rbf_f,
                                            (const float4*)geo, filt_w, filt_b,
                                            s_a, v_a);
    node_vupd_mfma<false><<<NN / 16, 512, 0, stream>>>(s_a, v_a, pv, node_gi, g,
                                                       uwt, vwt, u1t, u2t,
                                                       upd_b1, upd_b2,
                                                       w1th, w1tl, phi_b1,
                                                       w2th, w2tl, phi_b2);

    out_mlp<<<NG, 128, 0, stream>>>(g, out_w1, out_b1, out_w2, out_b2, (float*)d_out);
}

// Round 21
// 593.262 us; speedup vs baseline: 1.0107x; 1.0107x over previous
//
#include <hip/hip_runtime.h>

#define NN 20000
#define NE 320000
#define NG 64
#define D 128
#define D3 384
#define NRBF 20
#define RBF_ROW 24       // fp32 per rbf row -> 96B, 16B-aligned
#define PI_F 3.14159265358979323846f
#define RCUT 10.0f

typedef unsigned int uint;
typedef unsigned short ushort;
typedef __attribute__((ext_vector_type(8))) short bf16x8;
typedef __attribute__((ext_vector_type(4))) float f32x4;
typedef __attribute__((ext_vector_type(2))) float v2f;

__device__ __forceinline__ float silu_f(float x) {
    return x / (1.0f + __expf(-x));
}
__device__ __forceinline__ float b2f(ushort u) {
    return __uint_as_float(((uint)u) << 16);
}
__device__ __forceinline__ ushort f2b(float f) {
    uint u = __float_as_uint(f);
    u = u + 0x7fffu + ((u >> 16) & 1u);
    return (ushort)(u >> 16);
}
__device__ __forceinline__ float plo(uint u) { return __uint_as_float(u << 16); }
__device__ __forceinline__ float phi_(uint u) { return __uint_as_float(u & 0xffff0000u); }

#define MFMA3(acc, aH, aL, bH, bL)                                          \
    acc = __builtin_amdgcn_mfma_f32_16x16x32_bf16(aL, bH, acc, 0, 0, 0);    \
    acc = __builtin_amdgcn_mfma_f32_16x16x32_bf16(aH, bL, acc, 0, 0, 0);    \
    acc = __builtin_amdgcn_mfma_f32_16x16x32_bf16(aH, bH, acc, 0, 0, 0);

// ---------------------------------------------------------------- mega init
__global__ __launch_bounds__(256) void mega_init(
    float* __restrict__ g, int* __restrict__ deg,
    const float* __restrict__ pw1, const float* __restrict__ pw2,
    ushort* __restrict__ w1th, ushort* __restrict__ w1tl,
    ushort* __restrict__ w2th, ushort* __restrict__ w2tl,
    const float* __restrict__ Uw, const float* __restrict__ Vw,
    const float* __restrict__ uw1, const float* __restrict__ uw2,
    ushort* __restrict__ uwt, ushort* __restrict__ vwt,
    ushort* __restrict__ u1t, ushort* __restrict__ u2t)
{
    int stride = gridDim.x * blockDim.x;
    int idx0 = blockIdx.x * blockDim.x + threadIdx.x;
    for (int i = idx0; i < NG * D; i += stride) g[i] = 0.f;
    for (int i = idx0; i < NN; i += stride) deg[i] = 0;
    for (int i = idx0; i < D * D; i += stride) {
        int j = i >> 7, k = i & 127;
        float x = pw1[k * D + j]; ushort h = f2b(x);
        w1th[i] = h; w1tl[i] = f2b(x - b2f(h));
        float a = Uw[k * D + j]; ushort ha = f2b(a);
        uwt[i] = ha; uwt[D * D + i] = f2b(a - b2f(ha));
        float b = Vw[k * D + j]; ushort hb = f2b(b);
        vwt[i] = hb; vwt[D * D + i] = f2b(b - b2f(hb));
    }
    for (int i = idx0; i < D3 * D; i += stride) {
        int j = i >> 7, k = i & 127;
        float x = pw2[k * D3 + j]; ushort h = f2b(x);
        w2th[i] = h; w2tl[i] = f2b(x - b2f(h));
        float y = uw2[k * D3 + j]; ushort hy = f2b(y);
        u2t[i] = hy; u2t[D3 * D + i] = f2b(y - b2f(hy));
    }
    for (int i = idx0; i < 2 * D * D; i += stride) {
        int j = i >> 8, k = i & 255;
        float x = uw1[k * D + j]; ushort h = f2b(x);
        u1t[i] = h; u1t[2 * D * D + i] = f2b(x - b2f(h));
    }
}

// ---------------------------------------------------------------- CSR count
__global__ __launch_bounds__(256) void csr_count(
    const int* __restrict__ dst, int* __restrict__ deg)
{
    int e = blockIdx.x * blockDim.x + threadIdx.x;
    if (e < NE) atomicAdd(&deg[dst[e]], 1);
}

// ---------------------------------------------------------------- scan (CSR offsets + degree-bucket positions)
__global__ __launch_bounds__(1024) void scan_all(
    const int* __restrict__ deg, int* __restrict__ offs,
    int* __restrict__ cursor, int* __restrict__ bpos)
{
    __shared__ int part[1024];
    __shared__ int bc[64];
    int t = threadIdx.x;
    if (t < 64) bc[t] = 0;
    __syncthreads();
    const int per = (NN + 1023) / 1024;  // 20
    int base = t * per;
    int sum = 0;
    for (int i = 0; i < per; i++) {
        int idx = base + i;
        if (idx < NN) {
            int dg = deg[idx];
            sum += dg;
            int b = dg > 63 ? 63 : dg;
            atomicAdd(&bc[b], 1);
        }
    }
    part[t] = sum;
    __syncthreads();
    for (int off = 1; off < 1024; off <<= 1) {
        int vv = (t >= off) ? part[t - off] : 0;
        __syncthreads();
        part[t] += vv;
        __syncthreads();
    }
    int run = part[t] - sum;
    for (int i = 0; i < per; i++) {
        int idx = base + i;
        if (idx < NN) {
            offs[idx] = run;
            cursor[idx] = run;
            run += deg[idx];
        }
    }
    if (t == 1023) offs[NN] = run;
    __syncthreads();
    if (t == 0) {
        int r2 = 0;
        for (int b = 63; b >= 0; b--) { bpos[b] = r2; r2 += bc[b]; }  // descending degree
    }
}

// ---------------------------------------------------------------- geometry + CSR scatter
__global__ __launch_bounds__(256) void geom_scatter(
    const float* __restrict__ evec, const int* __restrict__ dst,
    const int* __restrict__ srcv, const int* __restrict__ atype,
    int* __restrict__ cursor,
    float* __restrict__ rbf, float4* __restrict__ geo,
    int* __restrict__ src_csr, int* __restrict__ styp_csr,
    const int* __restrict__ deg, int* __restrict__ bpos, int* __restrict__ perm)
{
    int e = blockIdx.x * blockDim.x + threadIdx.x;
    if (e < NE) {
        int p = atomicAdd(&cursor[dst[e]], 1);
        float x = evec[e * 3 + 0], y = evec[e * 3 + 1], z = evec[e * 3 + 2];
        float r = sqrtf(x * x + y * y + z * z);
        float inv = 1.0f / r;
        float f = (r < RCUT) ? 0.5f * (cosf(PI_F * r / RCUT) + 1.0f) : 0.0f;
        float4 gg;
        gg.x = x * inv; gg.y = y * inv; gg.z = z * inv; gg.w = f;
        geo[p] = gg;
        int sn = srcv[e];
        src_csr[p] = sn;
        styp_csr[p] = atype[sn];
        float base = PI_F * r / RCUT;
        float sf = inv * f;
        #pragma unroll
        for (int k = 0; k < NRBF; k++) {
            rbf[(size_t)p * RBF_ROW + k] = sinf((float)(k + 1) * base) * sf;
        }
    }
    if (e < NN) {
        int b = deg[e]; if (b > 63) b = 63;
        int p = atomicAdd(&bpos[b], 1);
        perm[p] = e;
    }
}

// ---------------------------------------------------------------- phi table (round 0)
__global__ __launch_bounds__(128) void phi10(
    const float* __restrict__ emb,
    const float* __restrict__ w1, const float* __restrict__ b1,
    const float* __restrict__ w2, const float* __restrict__ b2,
    uint* __restrict__ ptab)
{
    __shared__ float el[D];
    __shared__ float hl[D];
    int t = blockIdx.x, j = threadIdx.x;
    el[j] = emb[t * D + j];
    __syncthreads();
    float acc = b1[j];
    for (int k = 0; k < D; k++) acc += el[k] * w1[k * D + j];
    hl[j] = silu_f(acc);
    __syncthreads();
    float a1 = b2[D + j], a2 = b2[2 * D + j];
    for (int k = 0; k < D; k++) {
        float h = hl[k];
        a1 += h * w2[k * D3 + D + j];
        a2 += h * w2[k * D3 + 2 * D + j];
    }
    ptab[t * D + j] = (uint)f2b(a1) | ((uint)f2b(a2) << 16);
}

// ---------------------------------------------------------------- node gather round 0 (v=0; CSR-sequential)
// waves_per_eu(4,4): REQUIRED — the weight-resident design (60 VGPR of filter
// columns + temps ≈ 95 regs) spills at ANY higher wave target. Verified three
// times: R4 (290MB scratch), R9 (200MB), R19 (160MB @ (6,6)).
__global__ __launch_bounds__(512)
__attribute__((amdgpu_waves_per_eu(4, 4)))
void node_gather_r0(
    const int* __restrict__ offs,
    const int* __restrict__ perm, const int* __restrict__ styp_csr,
    const int* __restrict__ atype, const float* __restrict__ emb,
    const uint* __restrict__ ptab,
    const float* __restrict__ rbf, const float4* __restrict__ geo,
    const float* __restrict__ filt_w, const float* __restrict__ filt_b,
    float* __restrict__ s_new, float* __restrict__ v_new)
{
    int wave = threadIdx.x >> 6;
    int lane = threadIdx.x & 63;
    int widx = blockIdx.x * 4 + (wave >> 1);
    if (widx >= NN) return;
    int node = __builtin_amdgcn_readfirstlane(perm[widx]);
    int half = wave & 1;
    int d = half * 64 + lane;

    v2f wr1v[10], wr2v[10];
    #pragma unroll
    for (int m = 0; m < 10; m++) {
        wr1v[m] = (v2f){filt_w[(2 * m) * D3 + D + d],     filt_w[(2 * m + 1) * D3 + D + d]};
        wr2v[m] = (v2f){filt_w[(2 * m) * D3 + 2 * D + d], filt_w[(2 * m + 1) * D3 + 2 * D + d]};
    }
    float fb1 = filt_b[D + d], fb2 = filt_b[2 * D + d];
    int e0 = __builtin_amdgcn_readfirstlane(offs[node]);
    int e1 = __builtin_amdgcn_readfirstlane(offs[node + 1]);

    float acc_s = 0.f, av0 = 0.f, av1 = 0.f, av2 = 0.f;

    for (int i = e0; i < e1; i += 2) {
        bool hb = (i + 1 < e1);
        int ib = hb ? i + 1 : i;
        float mb = hb ? 1.0f : 0.0f;
        int ta = __builtin_amdgcn_readfirstlane(styp_csr[i]);
        int tb = __builtin_amdgcn_readfirstlane(styp_csr[ib]);
        float4 ga = geo[i];
        float4 gb = geo[ib];
        const float* rpa = rbf + (size_t)i * RBF_ROW;
        const float* rpb = rbf + (size_t)ib * RBF_ROW;
        uint pka = ptab[ta * D + d];
        uint pkb = ptab[tb * D + d];

        v2f Wa1v = {0.f, 0.f}, Wa2v = {0.f, 0.f};
        v2f Wb1v = {0.f, 0.f}, Wb2v = {0.f, 0.f};
        #pragma unroll
        for (int m = 0; m < 10; m++) {
            float2 ra2 = *(const float2*)(rpa + 2 * m);
            float2 rb2 = *(const float2*)(rpb + 2 * m);
            v2f rav = {ra2.x, ra2.y};
            v2f rbv = {rb2.x, rb2.y};
            Wa1v += rav * wr1v[m]; Wa2v += rav * wr2v[m];
            Wb1v += rbv * wr1v[m]; Wb2v += rbv * wr2v[m];
        }
        float Wa1 = Wa1v.x + Wa1v.y + ga.w * fb1;
        float Wa2 = Wa2v.x + Wa2v.y + ga.w * fb2;
        float Wb1 = Wb1v.x + Wb1v.y + gb.w * fb1;
        float Wb2 = Wb2v.x + Wb2v.y + gb.w * fb2;

        float pa1 = plo(pka), pa2 = phi_(pka);
        float pb1 = plo(pkb), pb2 = phi_(pkb);

        float m2a = pa1 * Wa1, m3a = pa2 * Wa2;
        float m2b = pb1 * Wb1 * mb, m3b = pb2 * Wb2 * mb;
        acc_s += m2a + m2b;
        av0 += ga.x * m3a + gb.x * m3b;
        av1 += ga.y * m3a + gb.y * m3b;
        av2 += ga.z * m3a + gb.z * m3b;
    }

    int tn = __builtin_amdgcn_readfirstlane(atype[node]);
    s_new[node * D + d] = emb[tn * D + d] + acc_s;
    v_new[(node * 3 + 0) * D + d] = av0;
    v_new[(node * 3 + 1) * D + d] = av1;
    v_new[(node * 3 + 2) * D + d] = av2;
}

// ---------------------------------------------------------------- node gather (round 1; CSR-sequential)
__global__ __launch_bounds__(512)
__attribute__((amdgpu_waves_per_eu(4, 4)))
void node_gather(
    const int* __restrict__ offs,
    const int* __restrict__ perm, const int* __restrict__ src_csr,
    const ushort* __restrict__ pv,
    const float* __restrict__ s_old, const float* __restrict__ v_old,
    const float* __restrict__ rbf, const float4* __restrict__ geo,
    const float* __restrict__ filt_w, const float* __restrict__ filt_b,
    float* __restrict__ s_new, float* __restrict__ v_new)
{
    int wave = threadIdx.x >> 6;
    int lane = threadIdx.x & 63;
    int widx = blockIdx.x * 4 + (wave >> 1);
    if (widx >= NN) return;
    int node = __builtin_amdgcn_readfirstlane(perm[widx]);
    int half = wave & 1;
    int d = half * 64 + lane;

    v2f wr0v[10], wr1v[10], wr2v[10];
    #pragma unroll
    for (int m = 0; m < 10; m++) {
        wr0v[m] = (v2f){filt_w[(2 * m) * D3 + d],         filt_w[(2 * m + 1) * D3 + d]};
        wr1v[m] = (v2f){filt_w[(2 * m) * D3 + D + d],     filt_w[(2 * m + 1) * D3 + D + d]};
        wr2v[m] = (v2f){filt_w[(2 * m) * D3 + 2 * D + d], filt_w[(2 * m + 1) * D3 + 2 * D + d]};
    }
    float fb0 = filt_b[d], fb1 = filt_b[D + d], fb2 = filt_b[2 * D + d];
    int e0 = __builtin_amdgcn_readfirstlane(offs[node]);
    int e1 = __builtin_amdgcn_readfirstlane(offs[node + 1]);

    float acc_s = 0.f, av0 = 0.f, av1 = 0.f, av2 = 0.f;
    size_t doff = (size_t)d * 6;

    for (int i = e0; i < e1; i += 2) {
        bool hb = (i + 1 < e1);
        int ib = hb ? i + 1 : i;
        float mb = hb ? 1.0f : 0.0f;
        int sa = __builtin_amdgcn_readfirstlane(src_csr[i]);
        int sb = __builtin_amdgcn_readfirstlane(src_csr[ib]);
        float4 ga = geo[i];
        float4 gb = geo[ib];
        const float* rpa = rbf + (size_t)i * RBF_ROW;
        const float* rpb = rbf + (size_t)ib * RBF_ROW;
        uint3 pka = *(const uint3*)(pv + (size_t)sa * 768 + doff);
        uint3 pkb = *(const uint3*)(pv + (size_t)sb * 768 + doff);

        v2f Wa0v = {0.f, 0.f}, Wa1v = {0.f, 0.f}, Wa2v = {0.f, 0.f};
        v2f Wb0v = {0.f, 0.f}, Wb1v = {0.f, 0.f}, Wb2v = {0.f, 0.f};
        #pragma unroll
        for (int m = 0; m < 10; m++) {
            float2 ra2 = *(const float2*)(rpa + 2 * m);
            float2 rb2 = *(const float2*)(rpb + 2 * m);
            v2f rav = {ra2.x, ra2.y};
            v2f rbv = {rb2.x, rb2.y};
            Wa0v += rav * wr0v[m]; Wa1v += rav * wr1v[m]; Wa2v += rav * wr2v[m];
            Wb0v += rbv * wr0v[m]; Wb1v += rbv * wr1v[m]; Wb2v += rbv * wr2v[m];
        }
        float Wa0 = Wa0v.x + Wa0v.y + ga.w * fb0;
        float Wa1 = Wa1v.x + Wa1v.y + ga.w * fb1;
        float Wa2 = Wa2v.x + Wa2v.y + ga.w * fb2;
        float Wb0 = Wb0v.x + Wb0v.y + gb.w * fb0;
        float Wb1 = Wb1v.x + Wb1v.y + gb.w * fb1;
        float Wb2 = Wb2v.x + Wb2v.y + gb.w * fb2;

        float pa0 = plo(pka.x), pa1 = phi_(pka.x), pa2 = plo(pka.y);
        float va0 = phi_(pka.y), va1 = plo(pka.z), va2 = phi_(pka.z);
        float pb0 = plo(pkb.x), pb1 = phi_(pkb.x), pb2 = plo(pkb.y);
        float vb0 = phi_(pkb.y), vb1 = plo(pkb.z), vb2 = phi_(pkb.z);

        float m1a = pa0 * Wa0, m2a = pa1 * Wa1, m3a = pa2 * Wa2;
        float m1b = pb0 * Wb0 * mb, m2b = pb1 * Wb1 * mb, m3b = pb2 * Wb2 * mb;
        acc_s += m2a + m2b;
        av0 += va0 * m1a + ga.x * m3a + vb0 * m1b + gb.x * m3b;
        av1 += va1 * m1a + ga.y * m3a + vb1 * m1b + gb.y * m3b;
        av2 += va2 * m1a + ga.z * m3a + vb2 * m1b + gb.z * m3b;
    }

    s_new[node * D + d] = s_old[node * D + d] + acc_s;
    v_new[(node * 3 + 0) * D + d] = v_old[(node * 3 + 0) * D + d] + av0;
    v_new[(node * 3 + 1) * D + d] = v_old[(node * 3 + 1) * D + d] + av1;
    v_new[(node * 3 + 2) * D + d] = v_old[(node * 3 + 2) * D + d] + av2;
}

// ---------------------------------------------------------------- fused update via MFMA bf16x3 (R18 verified)
template<bool FUSE>
__global__ __launch_bounds__(512) void node_vupd_mfma(
    float* __restrict__ s, float* __restrict__ v, ushort* __restrict__ pv,
    const int* __restrict__ gi, float* __restrict__ g,
    const ushort* __restrict__ uwt, const ushort* __restrict__ vwt,
    const ushort* __restrict__ u1t, const ushort* __restrict__ u2t,
    const float* __restrict__ ub1, const float* __restrict__ ub2,
    const ushort* __restrict__ w1th, const ushort* __restrict__ w1tl,
    const float* __restrict__ pb1,
    const ushort* __restrict__ w2th, const ushort* __restrict__ w2tl,
    const float* __restrict__ pb2)
{
    constexpr int U_BYTES = FUSE ? 13056 : 0;        // [48][136] bf16 (FUSE only)
    constexpr int UV_OFF  = U_BYTES;
    constexpr int B_OFF   = UV_OFF + 8448;           // UV: [16][132] f32
    constexpr int SMEM_SZ = B_OFF + 26112;           // region B (a/x/h or a_out[16][396])
    __shared__ __align__(16) char smem[SMEM_SZ];
    ushort* U_lds  = (ushort*)(smem);
    float*  UV_lds = (float*)(smem + UV_OFF);
    ushort* a_hi   = (ushort*)(smem + B_OFF);        // [48][136]
    ushort* a_lo   = a_hi + 48 * 136;
    ushort* x_hi   = (ushort*)(smem + B_OFF);        // [16][264]
    ushort* x_lo   = x_hi + 16 * 264;
    ushort* h_hi   = x_lo + 16 * 264;                // [16][136]
    ushort* h_lo   = h_hi + 16 * 136;
    float*  a_out  = (float*)(smem + B_OFF);         // [16][396] padded

    int tid = threadIdx.x;
    int wave = tid >> 6, lane = tid & 63;
    int arow = lane & 15, kg = lane >> 4;
    int n0 = blockIdx.x * 16;
    int jw = wave * 16 + arow;                       // this wave's j column

    // ---- phase 1: stage v (bf16 hi/lo)
    #pragma unroll
    for (int it = 0; it < 3; it++) {
        int f4 = it * 512 + tid;
        int row = f4 >> 5;
        int c4 = (f4 & 31) * 4;
        int i = row >> 4, n = row & 15;
        float4 vv = *(const float4*)&v[((size_t)(n0 + n) * 3 + i) * D + c4];
        ushort h0 = f2b(vv.x), h1 = f2b(vv.y), h2 = f2b(vv.z), h3 = f2b(vv.w);
        ushort l0 = f2b(vv.x - b2f(h0)), l1 = f2b(vv.y - b2f(h1));
        ushort l2 = f2b(vv.z - b2f(h2)), l3 = f2b(vv.w - b2f(h3));
        uint2 ph; ph.x = (uint)h0 | ((uint)h1 << 16); ph.y = (uint)h2 | ((uint)h3 << 16);
        uint2 pl; pl.x = (uint)l0 | ((uint)l1 << 16); pl.y = (uint)l2 | ((uint)l3 << 16);
        *(uint2*)&a_hi[row * 136 + c4] = ph;
        *(uint2*)&a_lo[row * 136 + c4] = pl;
    }
    __syncthreads();

    // ---- phase 2: U = v@Uw, Vp = v@Vw (one j-tile per wave)
    f32x4 accU[3], accVp[3];
    #pragma unroll
    for (int i = 0; i < 3; i++) {
        accU[i] = (f32x4){0.f, 0.f, 0.f, 0.f};
        accVp[i] = (f32x4){0.f, 0.f, 0.f, 0.f};
    }
    #pragma unroll
    for (int i = 0; i < 3; i++) {
        #pragma unroll
        for (int t = 0; t < 4; t++) {
            bf16x8 aH = *(const bf16x8*)&a_hi[(i * 16 + arow) * 136 + t * 32 + kg * 8];
            bf16x8 aL = *(const bf16x8*)&a_lo[(i * 16 + arow) * 136 + t * 32 + kg * 8];
            bf16x8 bH = *(const bf16x8*)&uwt[(size_t)jw * 128 + t * 32 + kg * 8];
            bf16x8 bL = *(const bf16x8*)&uwt[(size_t)D * D + (size_t)jw * 128 + t * 32 + kg * 8];
            MFMA3(accU[i], aH, aL, bH, bL)
            bf16x8 cH = *(const bf16x8*)&vwt[(size_t)jw * 128 + t * 32 + kg * 8];
            bf16x8 cL = *(const bf16x8*)&vwt[(size_t)D * D + (size_t)jw * 128 + t * 32 + kg * 8];
            MFMA3(accVp[i], aH, aL, cH, cL)
        }
    }
    __syncthreads();   // a reads done; region B reusable as x

    // ---- phase 3: U->LDS (FUSE), UV->LDS, Vn->x; stage s->x[:,128+]
    #pragma unroll
    for (int r = 0; r < 4; r++) {
        int n = kg * 4 + r;
        if (FUSE) {
            #pragma unroll
            for (int i = 0; i < 3; i++)
                U_lds[(i * 16 + n) * 136 + jw] = f2b(accU[i][r]);
        }
        float uv = accU[0][r] * accVp[0][r]
                 + accU[1][r] * accVp[1][r]
                 + accU[2][r] * accVp[2][r];
        float nn = accVp[0][r] * accVp[0][r]
                 + accVp[1][r] * accVp[1][r]
                 + accVp[2][r] * accVp[2][r];
        UV_lds[n * 132 + jw] = uv;
        float vn = sqrtf(nn);
        ushort hh = f2b(vn);
        x_hi[n * 264 + jw] = hh;
        x_lo[n * 264 + jw] = f2b(vn - b2f(hh));
    }
    #pragma unroll
    for (int it = 0; it < 4; it++) {
        int t8 = it * 512 + tid;
        int n = t8 >> 7, j = t8 & 127;
        float sv = s[(size_t)(n0 + n) * D + j];
        ushort hh = f2b(sv);
        x_hi[n * 264 + 128 + j] = hh;
        x_lo[n * 264 + 128 + j] = f2b(sv - b2f(hh));
    }
    __syncthreads();

    // ---- phase 4: layer 1 (K=256) -> h
    {
        f32x4 acc1 = (f32x4){0.f, 0.f, 0.f, 0.f};
        #pragma unroll
        for (int t = 0; t < 8; t++) {
            bf16x8 aH = *(const bf16x8*)&x_hi[arow * 264 + t * 32 + kg * 8];
            bf16x8 aL = *(const bf16x8*)&x_lo[arow * 264 + t * 32 + kg * 8];
            bf16x8 bH = *(const bf16x8*)&u1t[(size_t)jw * 256 + t * 32 + kg * 8];
            bf16x8 bL = *(const bf16x8*)&u1t[(size_t)2 * D * D + (size_t)jw * 256 + t * 32 + kg * 8];
            MFMA3(acc1, aH, aL, bH, bL)
        }
        float bias = ub1[jw];
        #pragma unroll
        for (int r = 0; r < 4; r++) {
            int n = kg * 4 + r;
            float hv = silu_f(acc1[r] + bias);
            ushort hh = f2b(hv);
            h_hi[n * 136 + jw] = hh;
            h_lo[n * 136 + jw] = f2b(hv - b2f(hh));
        }
    }
    __syncthreads();

    // ---- phase 5: layer 2 (N=384, 3 tiles per wave) -> a_out
    f32x4 acc2[3];
    #pragma unroll
    for (int q = 0; q < 3; q++) acc2[q] = (f32x4){0.f, 0.f, 0.f, 0.f};
    #pragma unroll
    for (int t = 0; t < 4; t++) {
        bf16x8 aH = *(const bf16x8*)&h_hi[arow * 136 + t * 32 + kg * 8];
        bf16x8 aL = *(const bf16x8*)&h_lo[arow * 136 + t * 32 + kg * 8];
        #pragma unroll
        for (int q = 0; q < 3; q++) {
            int j = (wave * 3 + q) * 16 + arow;
            bf16x8 bH = *(const bf16x8*)&u2t[(size_t)j * 128 + t * 32 + kg * 8];
            bf16x8 bL = *(const bf16x8*)&u2t[(size_t)D3 * D + (size_t)j * 128 + t * 32 + kg * 8];
            MFMA3(acc2[q], aH, aL, bH, bL)
        }
    }
    __syncthreads();   // x/h reads done; a_out may overwrite
    #pragma unroll
    for (int q = 0; q < 3; q++) {
        int j = (wave * 3 + q) * 16 + arow;
        float bias = ub2[j];
        #pragma unroll
        for (int r = 0; r < 4; r++)
            a_out[(kg * 4 + r) * 396 + j] = acc2[q][r] + bias;
    }
    __syncthreads();

    // ---- epilogue (coalesced)
    float snew_reg[4];
    #pragma unroll
    for (int it = 0; it < 4; it++) {
        int t8 = it * 512 + tid;
        int n = t8 >> 7, j = t8 & 127;
        float a1 = a_out[n * 396 + 128 + j];
        float a2 = a_out[n * 396 + 256 + j];
        size_t sidx = (size_t)(n0 + n) * D + j;
        float snew = s[sidx] + a2 + UV_lds[n * 132 + j] * a1;
        if (FUSE) {
            float a0 = a_out[n * 396 + j];
            s[sidx] = snew;
            snew_reg[it] = snew;
            ushort* pvp = pv + ((size_t)(n0 + n) * 128 + j) * 6;
            #pragma unroll
            for (int i = 0; i < 3; i++) {
                size_t idx = ((size_t)(n0 + n) * 3 + i) * D + j;
                float vf = v[idx] + b2f(U_lds[(i * 16 + n) * 136 + j]) * a0;
                v[idx] = vf;
                pvp[3 + i] = f2b(vf);
            }
        } else {
            int gn = gi[n0 + n];
            atomicAdd(&g[(size_t)gn * D + j], snew);
        }
    }

    if (!FUSE) return;

    // ---- fused phi for next round: pv[slot 0..2] = phi(s_new)
    __syncthreads();
    #pragma unroll
    for (int it = 0; it < 4; it++) {
        int t8 = it * 512 + tid;
        int n = t8 >> 7, j = t8 & 127;
        float sv = snew_reg[it];
        ushort hh = f2b(sv);
        x_hi[n * 264 + j] = hh;
        x_lo[n * 264 + j] = f2b(sv - b2f(hh));
    }
    __syncthreads();

    {
        f32x4 accp = (f32x4){0.f, 0.f, 0.f, 0.f};
        #pragma unroll
        for (int t = 0; t < 4; t++) {
            bf16x8 aH = *(const bf16x8*)&x_hi[arow * 264 + t * 32 + kg * 8];
            bf16x8 aL = *(const bf16x8*)&x_lo[arow * 264 + t * 32 + kg * 8];
            bf16x8 bH = *(const bf16x8*)&w1th[(size_t)jw * 128 + t * 32 + kg * 8];
            bf16x8 bL = *(const bf16x8*)&w1tl[(size_t)jw * 128 + t * 32 + kg * 8];
            MFMA3(accp, aH, aL, bH, bL)
        }
        __syncthreads();
        float bias = pb1[jw];
        #pragma unroll
        for (int r = 0; r < 4; r++) {
            int n = kg * 4 + r;
            float hv = silu_f(accp[r] + bias);
            ushort hh = f2b(hv);
            h_hi[n * 136 + jw] = hh;
            h_lo[n * 136 + jw] = f2b(hv - b2f(hh));
        }
    }
    __syncthreads();

    {
        f32x4 accq[3];
        #pragma unroll
        for (int q = 0; q < 3; q++) accq[q] = (f32x4){0.f, 0.f, 0.f, 0.f};
        #pragma unroll
        for (int t = 0; t < 4; t++) {
            bf16x8 aH = *(const bf16x8*)&h_hi[arow * 136 + t * 32 + kg * 8];
            bf16x8 aL = *(const bf16x8*)&h_lo[arow * 136 + t * 32 + kg * 8];
            #pragma unroll
            for (int q = 0; q < 3; q++) {
                int j = (wave * 3 + q) * 16 + arow;
                bf16x8 bH = *(const bf16x8*)&w2th[(size_t)j * 128 + t * 32 + kg * 8];
                bf16x8 bL = *(const bf16x8*)&w2tl[(size_t)j * 128 + t * 32 + kg * 8];
                MFMA3(accq[q], aH, aL, bH, bL)
            }
        }
        #pragma unroll
        for (int q = 0; q < 3; q++) {
            int j = (wave * 3 + q) * 16 + arow;
            float bias = pb2[j];
            int seg = j >> 7;
            int ch  = j & 127;
            #pragma unroll
            for (int r = 0; r < 4; r++) {
                pv[((size_t)(n0 + kg * 4 + r) * 128 + ch) * 6 + seg] = f2b(accq[q][r] + bias);
            }
        }
    }
}

// ---------------------------------------------------------------- readout
__global__ __launch_bounds__(128) void out_mlp(
    const float* __restrict__ g,
    const float* __restrict__ w1, const float* __restrict__ b1,
    const float* __restrict__ w2, const float* __restrict__ b2,
    float* __restrict__ out)
{
    __shared__ float gl[D];
    __shared__ float red[2];
    int j = threadIdx.x;
    int gr = blockIdx.x;
    gl[j] = g[gr * D + j];
    __syncthreads();
    float acc = b1[j];
    for (int k = 0; k < D; k++) acc += gl[k] * w1[k * D + j];
    float h = silu_f(acc) * w2[j];
    #pragma unroll
    for (int off = 32; off >= 1; off >>= 1) h += __shfl_down(h, off);
    if ((j & 63) == 0) red[j >> 6] = h;
    __syncthreads();
    if (j == 0) out[gr] = red[0] + red[1] + b2[0];
}

// ================================================================ launch
extern "C" void kernel_launch(void* const* d_in, const int* in_sizes, int n_in,
                              void* d_out, int out_size, void* d_ws, size_t ws_size,
                              hipStream_t stream)
{
    const int*   edge_src   = (const int*)  d_in[0];
    const int*   edge_dst   = (const int*)  d_in[1];
    const float* edge_vec   = (const float*)d_in[2];
    const int*   atom_types = (const int*)  d_in[3];
    const int*   node_gi    = (const int*)  d_in[4];
    const float* embedding  = (const float*)d_in[5];
    const float* phi_w1     = (const float*)d_in[6];
    const float* phi_b1     = (const float*)d_in[7];
    const float* phi_w2     = (const float*)d_in[8];
    const float* phi_b2     = (const float*)d_in[9];
    const float* filt_w     = (const float*)d_in[10];
    const float* filt_b     = (const float*)d_in[11];
    const float* upd_w1     = (const float*)d_in[12];
    const float* upd_b1     = (const float*)d_in[13];
    const float* upd_w2     = (const float*)d_in[14];
    const float* upd_b2     = (const float*)d_in[15];
    const float* U_w        = (const float*)d_in[16];
    const float* V_w        = (const float*)d_in[17];
    const float* out_w1     = (const float*)d_in[18];
    const float* out_b1     = (const float*)d_in[19];
    const float* out_w2     = (const float*)d_in[20];
    const float* out_b2     = (const float*)d_in[21];

    float* ws = (float*)d_ws;
    size_t o = 0;
    float* s_a   = ws + o; o += (size_t)NN * D;
    float* s_b   = ws + o; o += (size_t)NN * D;
    float* v_a   = ws + o; o += (size_t)NN * 3 * D;
    float* v_b   = ws + o; o += (size_t)NN * 3 * D;
    float* pv_f  = ws + o; o += (size_t)NN * 384;             // pv: [n][128][6] bf16
    float* rbf_f = ws + o; o += (size_t)NE * RBF_ROW;         // fp32, CSR order
    float* geo   = ws + o; o += (size_t)NE * 4;               // CSR order
    float* g     = ws + o; o += (size_t)NG * D;
    float* w1t_f = ws + o; o += (size_t)D * D;                // phi w1 hi+lo
    float* w2t_f = ws + o; o += (size_t)D3 * D;               // phi w2 hi+lo
    float* uwt_f = ws + o; o += (size_t)D * D;                // Uw^T hi+lo
    float* vwt_f = ws + o; o += (size_t)D * D;                // Vw^T hi+lo
    float* u1t_f = ws + o; o += (size_t)2 * D * D;            // upd_w1^T hi+lo
    float* u2t_f = ws + o; o += (size_t)D3 * D;               // upd_w2^T hi+lo
    float* ptab_f= ws + o; o += (size_t)10 * D;               // round-0 phi table
    int* deg     = (int*)(ws + o); o += NN;
    int* offs    = (int*)(ws + o); o += NN + 1;
    int* cursor  = (int*)(ws + o); o += NN;
    int* perm    = (int*)(ws + o); o += NN;
    int* bpos    = (int*)(ws + o); o += 64;
    int* src_csr = (int*)(ws + o); o += NE;
    int* styp_csr= (int*)(ws + o); o += NE;

    ushort* pv    = (ushort*)pv_f;
    ushort* w1th  = (ushort*)w1t_f;
    ushort* w1tl  = w1th + (size_t)D * D;
    ushort* w2th  = (ushort*)w2t_f;
    ushort* w2tl  = w2th + (size_t)D3 * D;
    ushort* uwt   = (ushort*)uwt_f;
    ushort* vwt   = (ushort*)vwt_f;
    ushort* u1t   = (ushort*)u1t_f;
    ushort* u2t   = (ushort*)u2t_f;
    uint*   ptab  = (uint*)ptab_f;

    mega_init<<<512, 256, 0, stream>>>(g, deg, phi_w1, phi_w2,
                                       w1th, w1tl, w2th, w2tl,
                                       U_w, V_w, upd_w1, upd_w2,
                                       uwt, vwt, u1t, u2t);
    csr_count<<<(NE + 255) / 256, 256, 0, stream>>>(edge_dst, deg);
    scan_all<<<1, 1024, 0, stream>>>(deg, offs, cursor, bpos);
    geom_scatter<<<(NE + 255) / 256, 256, 0, stream>>>(edge_vec, edge_dst, edge_src,
                                                       atom_types, cursor,
                                                       rbf_f, (float4*)geo,
                                                       src_csr, styp_csr,
                                                       deg, bpos, perm);
    phi10<<<10, 128, 0, stream>>>(embedding, phi_w1, phi_b1, phi_w2, phi_b2, ptab);

    // round 0 (v = 0 specialization)
    node_gather_r0<<<NN / 4, 512, 0, stream>>>(offs, perm, styp_csr,
                                               atom_types, embedding, ptab,
                                               rbf_f, (const float4*)geo,
                                               filt_w, filt_b, s_b, v_b);
    node_vupd_mfma<true><<<NN / 16, 512, 0, stream>>>(s_b, v_b, pv, node_gi, g,
                                                      uwt, vwt, u1t, u2t,
                                                      upd_b1, upd_b2,
                                                      w1th, w1tl, phi_b1,
                                                      w2th, w2tl, phi_b2);
    // round 1
    node_gather<<<NN / 4, 512, 0, stream>>>(offs, perm, src_csr, pv,
                                            s_b, v_b, rbf_f,
                                            (const float4*)geo, filt_w, filt_b,
                                            s_a, v_a);
    node_vupd_mfma<false><<<NN / 16, 512, 0, stream>>>(s_a, v_a, pv, node_gi, g,
                                                       uwt, vwt, u1t, u2t,
                                                       upd_b1, upd_b2,
                                                       w1th, w1tl, phi_b1,
                                                       w2th, w2tl, phi_b2);

    out_mlp<<<NG, 128, 0, stream>>>(g, out_w1, out_b1, out_w2, out_b2, (float*)d_out);
}

// Round 22
// 591.330 us; speedup vs baseline: 1.0140x; 1.0033x over previous
//
#include <hip/hip_runtime.h>

#define NN 20000
#define NE 320000
#define NG 64
#define D 128
#define D3 384
#define NRBF 20
#define RBF_ROW 24       // fp32 per rbf row -> 96B, 16B-aligned
#define PI_F 3.14159265358979323846f
#define RCUT 10.0f

typedef unsigned int uint;
typedef unsigned short ushort;
typedef __attribute__((ext_vector_type(8))) short bf16x8;
typedef __attribute__((ext_vector_type(4))) float f32x4;
typedef __attribute__((ext_vector_type(2))) float v2f;

__device__ __forceinline__ float silu_f(float x) {
    return x / (1.0f + __expf(-x));
}
__device__ __forceinline__ float b2f(ushort u) {
    return __uint_as_float(((uint)u) << 16);
}
__device__ __forceinline__ ushort f2b(float f) {
    uint u = __float_as_uint(f);
    u = u + 0x7fffu + ((u >> 16) & 1u);
    return (ushort)(u >> 16);
}
__device__ __forceinline__ float plo(uint u) { return __uint_as_float(u << 16); }
__device__ __forceinline__ float phi_(uint u) { return __uint_as_float(u & 0xffff0000u); }

#define MFMA3(acc, aH, aL, bH, bL)                                          \
    acc = __builtin_amdgcn_mfma_f32_16x16x32_bf16(aL, bH, acc, 0, 0, 0);    \
    acc = __builtin_amdgcn_mfma_f32_16x16x32_bf16(aH, bL, acc, 0, 0, 0);    \
    acc = __builtin_amdgcn_mfma_f32_16x16x32_bf16(aH, bH, acc, 0, 0, 0);

// ---------------------------------------------------------------- mega init
__global__ __launch_bounds__(256) void mega_init(
    float* __restrict__ g, int* __restrict__ deg,
    const float* __restrict__ pw1, const float* __restrict__ pw2,
    ushort* __restrict__ w1th, ushort* __restrict__ w1tl,
    ushort* __restrict__ w2th, ushort* __restrict__ w2tl,
    const float* __restrict__ Uw, const float* __restrict__ Vw,
    const float* __restrict__ uw1, const float* __restrict__ uw2,
    ushort* __restrict__ uwt, ushort* __restrict__ vwt,
    ushort* __restrict__ u1t, ushort* __restrict__ u2t)
{
    int stride = gridDim.x * blockDim.x;
    int idx0 = blockIdx.x * blockDim.x + threadIdx.x;
    for (int i = idx0; i < NG * D; i += stride) g[i] = 0.f;
    for (int i = idx0; i < NN; i += stride) deg[i] = 0;
    for (int i = idx0; i < D * D; i += stride) {
        int j = i >> 7, k = i & 127;
        float x = pw1[k * D + j]; ushort h = f2b(x);
        w1th[i] = h; w1tl[i] = f2b(x - b2f(h));
        float a = Uw[k * D + j]; ushort ha = f2b(a);
        uwt[i] = ha; uwt[D * D + i] = f2b(a - b2f(ha));
        float b = Vw[k * D + j]; ushort hb = f2b(b);
        vwt[i] = hb; vwt[D * D + i] = f2b(b - b2f(hb));
    }
    for (int i = idx0; i < D3 * D; i += stride) {
        int j = i >> 7, k = i & 127;
        float x = pw2[k * D3 + j]; ushort h = f2b(x);
        w2th[i] = h; w2tl[i] = f2b(x - b2f(h));
        float y = uw2[k * D3 + j]; ushort hy = f2b(y);
        u2t[i] = hy; u2t[D3 * D + i] = f2b(y - b2f(hy));
    }
    for (int i = idx0; i < 2 * D * D; i += stride) {
        int j = i >> 8, k = i & 255;
        float x = uw1[k * D + j]; ushort h = f2b(x);
        u1t[i] = h; u1t[2 * D * D + i] = f2b(x - b2f(h));
    }
}

// ---------------------------------------------------------------- CSR count
__global__ __launch_bounds__(256) void csr_count(
    const int* __restrict__ dst, int* __restrict__ deg)
{
    int e = blockIdx.x * blockDim.x + threadIdx.x;
    if (e < NE) atomicAdd(&deg[dst[e]], 1);
}

// ---------------------------------------------------------------- scan (CSR offsets + degree-bucket positions)
__global__ __launch_bounds__(1024) void scan_all(
    const int* __restrict__ deg, int* __restrict__ offs,
    int* __restrict__ cursor, int* __restrict__ bpos)
{
    __shared__ int part[1024];
    __shared__ int bc[64];
    int t = threadIdx.x;
    if (t < 64) bc[t] = 0;
    __syncthreads();
    const int per = (NN + 1023) / 1024;  // 20
    int base = t * per;
    int sum = 0;
    for (int i = 0; i < per; i++) {
        int idx = base + i;
        if (idx < NN) {
            int dg = deg[idx];
            sum += dg;
            int b = dg > 63 ? 63 : dg;
            atomicAdd(&bc[b], 1);
        }
    }
    part[t] = sum;
    __syncthreads();
    for (int off = 1; off < 1024; off <<= 1) {
        int vv = (t >= off) ? part[t - off] : 0;
        __syncthreads();
        part[t] += vv;
        __syncthreads();
    }
    int run = part[t] - sum;
    for (int i = 0; i < per; i++) {
        int idx = base + i;
        if (idx < NN) {
            offs[idx] = run;
            cursor[idx] = run;
            run += deg[idx];
        }
    }
    if (t == 1023) offs[NN] = run;
    __syncthreads();
    if (t == 0) {
        int r2 = 0;
        for (int b = 63; b >= 0; b--) { bpos[b] = r2; r2 += bc[b]; }  // descending degree
    }
}

// ---------------------------------------------------------------- geometry + CSR scatter
__global__ __launch_bounds__(256) void geom_scatter(
    const float* __restrict__ evec, const int* __restrict__ dst,
    const int* __restrict__ srcv, const int* __restrict__ atype,
    int* __restrict__ cursor,
    float* __restrict__ rbf, float4* __restrict__ geo,
    int* __restrict__ src_csr, int* __restrict__ styp_csr,
    const int* __restrict__ deg, int* __restrict__ bpos, int* __restrict__ perm)
{
    int e = blockIdx.x * blockDim.x + threadIdx.x;
    if (e < NE) {
        int p = atomicAdd(&cursor[dst[e]], 1);
        float x = evec[e * 3 + 0], y = evec[e * 3 + 1], z = evec[e * 3 + 2];
        float r = sqrtf(x * x + y * y + z * z);
        float inv = 1.0f / r;
        float f = (r < RCUT) ? 0.5f * (cosf(PI_F * r / RCUT) + 1.0f) : 0.0f;
        float4 gg;
        gg.x = x * inv; gg.y = y * inv; gg.z = z * inv; gg.w = f;
        geo[p] = gg;
        int sn = srcv[e];
        src_csr[p] = sn;
        styp_csr[p] = atype[sn];
        float base = PI_F * r / RCUT;
        float sf = inv * f;
        #pragma unroll
        for (int k = 0; k < NRBF; k++) {
            rbf[(size_t)p * RBF_ROW + k] = sinf((float)(k + 1) * base) * sf;
        }
    }
    if (e < NN) {
        int b = deg[e]; if (b > 63) b = 63;
        int p = atomicAdd(&bpos[b], 1);
        perm[p] = e;
    }
}

// ---------------------------------------------------------------- phi table (round 0)
__global__ __launch_bounds__(128) void phi10(
    const float* __restrict__ emb,
    const float* __restrict__ w1, const float* __restrict__ b1,
    const float* __restrict__ w2, const float* __restrict__ b2,
    uint* __restrict__ ptab)
{
    __shared__ float el[D];
    __shared__ float hl[D];
    int t = blockIdx.x, j = threadIdx.x;
    el[j] = emb[t * D + j];
    __syncthreads();
    float acc = b1[j];
    for (int k = 0; k < D; k++) acc += el[k] * w1[k * D + j];
    hl[j] = silu_f(acc);
    __syncthreads();
    float a1 = b2[D + j], a2 = b2[2 * D + j];
    for (int k = 0; k < D; k++) {
        float h = hl[k];
        a1 += h * w2[k * D3 + D + j];
        a2 += h * w2[k * D3 + 2 * D + j];
    }
    ptab[t * D + j] = (uint)f2b(a1) | ((uint)f2b(a2) << 16);
}

// ---------------------------------------------------------------- node gather round 0 (v=0; CSR-sequential; R17 verified)
// waves_per_eu(4,4): REQUIRED — weight-resident design spills at any higher
// wave target. Verified: R4 (290MB scratch), R9 (200MB), R19 (160MB @ (6,6)).
__global__ __launch_bounds__(512)
__attribute__((amdgpu_waves_per_eu(4, 4)))
void node_gather_r0(
    const int* __restrict__ offs,
    const int* __restrict__ perm, const int* __restrict__ styp_csr,
    const int* __restrict__ atype, const float* __restrict__ emb,
    const uint* __restrict__ ptab,
    const float* __restrict__ rbf, const float4* __restrict__ geo,
    const float* __restrict__ filt_w, const float* __restrict__ filt_b,
    float* __restrict__ s_new, float* __restrict__ v_new)
{
    int wave = threadIdx.x >> 6;
    int lane = threadIdx.x & 63;
    int widx = blockIdx.x * 4 + (wave >> 1);
    if (widx >= NN) return;
    int node = __builtin_amdgcn_readfirstlane(perm[widx]);
    int half = wave & 1;
    int d = half * 64 + lane;

    v2f wr1v[10], wr2v[10];
    #pragma unroll
    for (int m = 0; m < 10; m++) {
        wr1v[m] = (v2f){filt_w[(2 * m) * D3 + D + d],     filt_w[(2 * m + 1) * D3 + D + d]};
        wr2v[m] = (v2f){filt_w[(2 * m) * D3 + 2 * D + d], filt_w[(2 * m + 1) * D3 + 2 * D + d]};
    }
    float fb1 = filt_b[D + d], fb2 = filt_b[2 * D + d];
    int e0 = __builtin_amdgcn_readfirstlane(offs[node]);
    int e1 = __builtin_amdgcn_readfirstlane(offs[node + 1]);

    float acc_s = 0.f, av0 = 0.f, av1 = 0.f, av2 = 0.f;

    for (int i = e0; i < e1; i += 2) {
        bool hb = (i + 1 < e1);
        int ib = hb ? i + 1 : i;
        float mb = hb ? 1.0f : 0.0f;
        int ta = __builtin_amdgcn_readfirstlane(styp_csr[i]);
        int tb = __builtin_amdgcn_readfirstlane(styp_csr[ib]);
        float4 ga = geo[i];
        float4 gb = geo[ib];
        const float* rpa = rbf + (size_t)i * RBF_ROW;
        const float* rpb = rbf + (size_t)ib * RBF_ROW;
        uint pka = ptab[ta * D + d];
        uint pkb = ptab[tb * D + d];

        v2f Wa1v = {0.f, 0.f}, Wa2v = {0.f, 0.f};
        v2f Wb1v = {0.f, 0.f}, Wb2v = {0.f, 0.f};
        #pragma unroll
        for (int m = 0; m < 10; m++) {
            float2 ra2 = *(const float2*)(rpa + 2 * m);
            float2 rb2 = *(const float2*)(rpb + 2 * m);
            v2f rav = {ra2.x, ra2.y};
            v2f rbv = {rb2.x, rb2.y};
            Wa1v += rav * wr1v[m]; Wa2v += rav * wr2v[m];
            Wb1v += rbv * wr1v[m]; Wb2v += rbv * wr2v[m];
        }
        float Wa1 = Wa1v.x + Wa1v.y + ga.w * fb1;
        float Wa2 = Wa2v.x + Wa2v.y + ga.w * fb2;
        float Wb1 = Wb1v.x + Wb1v.y + gb.w * fb1;
        float Wb2 = Wb2v.x + Wb2v.y + gb.w * fb2;

        float pa1 = plo(pka), pa2 = phi_(pka);
        float pb1 = plo(pkb), pb2 = phi_(pkb);

        float m2a = pa1 * Wa1, m3a = pa2 * Wa2;
        float m2b = pb1 * Wb1 * mb, m3b = pb2 * Wb2 * mb;
        acc_s += m2a + m2b;
        av0 += ga.x * m3a + gb.x * m3b;
        av1 += ga.y * m3a + gb.y * m3b;
        av2 += ga.z * m3a + gb.z * m3b;
    }

    int tn = __builtin_amdgcn_readfirstlane(atype[node]);
    s_new[node * D + d] = emb[tn * D + d] + acc_s;
    v_new[(node * 3 + 0) * D + d] = av0;
    v_new[(node * 3 + 1) * D + d] = av1;
    v_new[(node * 3 + 2) * D + d] = av2;
}

// ---------------------------------------------------------------- node gather (round 1; CSR-sequential + pv prefetch)
// R21: cross-iteration software pipeline — iteration i issues the scattered
// pv loads for iteration i+2 (src_csr is sequential/cheap; pv is the ~500cy
// random-access load). The 30 pk-FMA W-recompute of the current pair then
// overlaps the prefetch latency. +~8 VGPR, within the 4-wave budget.
__global__ __launch_bounds__(512)
__attribute__((amdgpu_waves_per_eu(4, 4)))
void node_gather(
    const int* __restrict__ offs,
    const int* __restrict__ perm, const int* __restrict__ src_csr,
    const ushort* __restrict__ pv,
    const float* __restrict__ s_old, const float* __restrict__ v_old,
    const float* __restrict__ rbf, const float4* __restrict__ geo,
    const float* __restrict__ filt_w, const float* __restrict__ filt_b,
    float* __restrict__ s_new, float* __restrict__ v_new)
{
    int wave = threadIdx.x >> 6;
    int lane = threadIdx.x & 63;
    int widx = blockIdx.x * 4 + (wave >> 1);
    if (widx >= NN) return;
    int node = __builtin_amdgcn_readfirstlane(perm[widx]);
    int half = wave & 1;
    int d = half * 64 + lane;

    v2f wr0v[10], wr1v[10], wr2v[10];
    #pragma unroll
    for (int m = 0; m < 10; m++) {
        wr0v[m] = (v2f){filt_w[(2 * m) * D3 + d],         filt_w[(2 * m + 1) * D3 + d]};
        wr1v[m] = (v2f){filt_w[(2 * m) * D3 + D + d],     filt_w[(2 * m + 1) * D3 + D + d]};
        wr2v[m] = (v2f){filt_w[(2 * m) * D3 + 2 * D + d], filt_w[(2 * m + 1) * D3 + 2 * D + d]};
    }
    float fb0 = filt_b[d], fb1 = filt_b[D + d], fb2 = filt_b[2 * D + d];
    int e0 = __builtin_amdgcn_readfirstlane(offs[node]);
    int e1 = __builtin_amdgcn_readfirstlane(offs[node + 1]);

    float acc_s = 0.f, av0 = 0.f, av1 = 0.f, av2 = 0.f;
    size_t doff = (size_t)d * 6;

    uint3 pka = {0, 0, 0}, pkb = {0, 0, 0};
    if (e0 < e1) {
        int ib0 = (e0 + 1 < e1) ? e0 + 1 : e0;
        int sa0 = __builtin_amdgcn_readfirstlane(src_csr[e0]);
        int sb0 = __builtin_amdgcn_readfirstlane(src_csr[ib0]);
        pka = *(const uint3*)(pv + (size_t)sa0 * 768 + doff);
        pkb = *(const uint3*)(pv + (size_t)sb0 * 768 + doff);
    }

    for (int i = e0; i < e1; i += 2) {
        bool hb = (i + 1 < e1);
        int ib = hb ? i + 1 : i;
        float mb = hb ? 1.0f : 0.0f;
        float4 ga = geo[i];
        float4 gb = geo[ib];
        const float* rpa = rbf + (size_t)i * RBF_ROW;
        const float* rpb = rbf + (size_t)ib * RBF_ROW;

        // prefetch next pair's pv (the ~500cy scattered loads)
        uint3 pka_n = pka, pkb_n = pkb;
        int inext = i + 2;
        if (inext < e1) {
            int ibn = (inext + 1 < e1) ? inext + 1 : inext;
            int sa_n = __builtin_amdgcn_readfirstlane(src_csr[inext]);
            int sb_n = __builtin_amdgcn_readfirstlane(src_csr[ibn]);
            pka_n = *(const uint3*)(pv + (size_t)sa_n * 768 + doff);
            pkb_n = *(const uint3*)(pv + (size_t)sb_n * 768 + doff);
        }

        v2f Wa0v = {0.f, 0.f}, Wa1v = {0.f, 0.f}, Wa2v = {0.f, 0.f};
        v2f Wb0v = {0.f, 0.f}, Wb1v = {0.f, 0.f}, Wb2v = {0.f, 0.f};
        #pragma unroll
        for (int m = 0; m < 10; m++) {
            float2 ra2 = *(const float2*)(rpa + 2 * m);
            float2 rb2 = *(const float2*)(rpb + 2 * m);
            v2f rav = {ra2.x, ra2.y};
            v2f rbv = {rb2.x, rb2.y};
            Wa0v += rav * wr0v[m]; Wa1v += rav * wr1v[m]; Wa2v += rav * wr2v[m];
            Wb0v += rbv * wr0v[m]; Wb1v += rbv * wr1v[m]; Wb2v += rbv * wr2v[m];
        }
        float Wa0 = Wa0v.x + Wa0v.y + ga.w * fb0;
        float Wa1 = Wa1v.x + Wa1v.y + ga.w * fb1;
        float Wa2 = Wa2v.x + Wa2v.y + ga.w * fb2;
        float Wb0 = Wb0v.x + Wb0v.y + gb.w * fb0;
        float Wb1 = Wb1v.x + Wb1v.y + gb.w * fb1;
        float Wb2 = Wb2v.x + Wb2v.y + gb.w * fb2;

        float pa0 = plo(pka.x), pa1 = phi_(pka.x), pa2 = plo(pka.y);
        float va0 = phi_(pka.y), va1 = plo(pka.z), va2 = phi_(pka.z);
        float pb0 = plo(pkb.x), pb1 = phi_(pkb.x), pb2 = plo(pkb.y);
        float vb0 = phi_(pkb.y), vb1 = plo(pkb.z), vb2 = phi_(pkb.z);

        float m1a = pa0 * Wa0, m2a = pa1 * Wa1, m3a = pa2 * Wa2;
        float m1b = pb0 * Wb0 * mb, m2b = pb1 * Wb1 * mb, m3b = pb2 * Wb2 * mb;
        acc_s += m2a + m2b;
        av0 += va0 * m1a + ga.x * m3a + vb0 * m1b + gb.x * m3b;
        av1 += va1 * m1a + ga.y * m3a + vb1 * m1b + gb.y * m3b;
        av2 += va2 * m1a + ga.z * m3a + vb2 * m1b + gb.z * m3b;

        pka = pka_n; pkb = pkb_n;
    }

    s_new[node * D + d] = s_old[node * D + d] + acc_s;
    v_new[(node * 3 + 0) * D + d] = v_old[(node * 3 + 0) * D + d] + av0;
    v_new[(node * 3 + 1) * D + d] = v_old[(node * 3 + 1) * D + d] + av1;
    v_new[(node * 3 + 2) * D + d] = v_old[(node * 3 + 2) * D + d] + av2;
}

// ---------------------------------------------------------------- fused update via MFMA bf16x3 (R18 verified)
template<bool FUSE>
__global__ __launch_bounds__(512) void node_vupd_mfma(
    float* __restrict__ s, float* __restrict__ v, ushort* __restrict__ pv,
    const int* __restrict__ gi, float* __restrict__ g,
    const ushort* __restrict__ uwt, const ushort* __restrict__ vwt,
    const ushort* __restrict__ u1t, const ushort* __restrict__ u2t,
    const float* __restrict__ ub1, const float* __restrict__ ub2,
    const ushort* __restrict__ w1th, const ushort* __restrict__ w1tl,
    const float* __restrict__ pb1,
    const ushort* __restrict__ w2th, const ushort* __restrict__ w2tl,
    const float* __restrict__ pb2)
{
    constexpr int U_BYTES = FUSE ? 13056 : 0;        // [48][136] bf16 (FUSE only)
    constexpr int UV_OFF  = U_BYTES;
    constexpr int B_OFF   = UV_OFF + 8448;           // UV: [16][132] f32
    constexpr int SMEM_SZ = B_OFF + 26112;           // region B (a/x/h or a_out[16][396])
    __shared__ __align__(16) char smem[SMEM_SZ];
    ushort* U_lds  = (ushort*)(smem);
    float*  UV_lds = (float*)(smem + UV_OFF);
    ushort* a_hi   = (ushort*)(smem + B_OFF);        // [48][136]
    ushort* a_lo   = a_hi + 48 * 136;
    ushort* x_hi   = (ushort*)(smem + B_OFF);        // [16][264]
    ushort* x_lo   = x_hi + 16 * 264;
    ushort* h_hi   = x_lo + 16 * 264;                // [16][136]
    ushort* h_lo   = h_hi + 16 * 136;
    float*  a_out  = (float*)(smem + B_OFF);         // [16][396] padded

    int tid = threadIdx.x;
    int wave = tid >> 6, lane = tid & 63;
    int arow = lane & 15, kg = lane >> 4;
    int n0 = blockIdx.x * 16;
    int jw = wave * 16 + arow;                       // this wave's j column

    // ---- phase 1: stage v (bf16 hi/lo)
    #pragma unroll
    for (int it = 0; it < 3; it++) {
        int f4 = it * 512 + tid;
        int row = f4 >> 5;
        int c4 = (f4 & 31) * 4;
        int i = row >> 4, n = row & 15;
        float4 vv = *(const float4*)&v[((size_t)(n0 + n) * 3 + i) * D + c4];
        ushort h0 = f2b(vv.x), h1 = f2b(vv.y), h2 = f2b(vv.z), h3 = f2b(vv.w);
        ushort l0 = f2b(vv.x - b2f(h0)), l1 = f2b(vv.y - b2f(h1));
        ushort l2 = f2b(vv.z - b2f(h2)), l3 = f2b(vv.w - b2f(h3));
        uint2 ph; ph.x = (uint)h0 | ((uint)h1 << 16); ph.y = (uint)h2 | ((uint)h3 << 16);
        uint2 pl; pl.x = (uint)l0 | ((uint)l1 << 16); pl.y = (uint)l2 | ((uint)l3 << 16);
        *(uint2*)&a_hi[row * 136 + c4] = ph;
        *(uint2*)&a_lo[row * 136 + c4] = pl;
    }
    __syncthreads();

    // ---- phase 2: U = v@Uw, Vp = v@Vw (one j-tile per wave)
    f32x4 accU[3], accVp[3];
    #pragma unroll
    for (int i = 0; i < 3; i++) {
        accU[i] = (f32x4){0.f, 0.f, 0.f, 0.f};
        accVp[i] = (f32x4){0.f, 0.f, 0.f, 0.f};
    }
    #pragma unroll
    for (int i = 0; i < 3; i++) {
        #pragma unroll
        for (int t = 0; t < 4; t++) {
            bf16x8 aH = *(const bf16x8*)&a_hi[(i * 16 + arow) * 136 + t * 32 + kg * 8];
            bf16x8 aL = *(const bf16x8*)&a_lo[(i * 16 + arow) * 136 + t * 32 + kg * 8];
            bf16x8 bH = *(const bf16x8*)&uwt[(size_t)jw * 128 + t * 32 + kg * 8];
            bf16x8 bL = *(const bf16x8*)&uwt[(size_t)D * D + (size_t)jw * 128 + t * 32 + kg * 8];
            MFMA3(accU[i], aH, aL, bH, bL)
            bf16x8 cH = *(const bf16x8*)&vwt[(size_t)jw * 128 + t * 32 + kg * 8];
            bf16x8 cL = *(const bf16x8*)&vwt[(size_t)D * D + (size_t)jw * 128 + t * 32 + kg * 8];
            MFMA3(accVp[i], aH, aL, cH, cL)
        }
    }
    __syncthreads();   // a reads done; region B reusable as x

    // ---- phase 3: U->LDS (FUSE), UV->LDS, Vn->x; stage s->x[:,128+]
    #pragma unroll
    for (int r = 0; r < 4; r++) {
        int n = kg * 4 + r;
        if (FUSE) {
            #pragma unroll
            for (int i = 0; i < 3; i++)
                U_lds[(i * 16 + n) * 136 + jw] = f2b(accU[i][r]);
        }
        float uv = accU[0][r] * accVp[0][r]
                 + accU[1][r] * accVp[1][r]
                 + accU[2][r] * accVp[2][r];
        float nn = accVp[0][r] * accVp[0][r]
                 + accVp[1][r] * accVp[1][r]
                 + accVp[2][r] * accVp[2][r];
        UV_lds[n * 132 + jw] = uv;
        float vn = sqrtf(nn);
        ushort hh = f2b(vn);
        x_hi[n * 264 + jw] = hh;
        x_lo[n * 264 + jw] = f2b(vn - b2f(hh));
    }
    #pragma unroll
    for (int it = 0; it < 4; it++) {
        int t8 = it * 512 + tid;
        int n = t8 >> 7, j = t8 & 127;
        float sv = s[(size_t)(n0 + n) * D + j];
        ushort hh = f2b(sv);
        x_hi[n * 264 + 128 + j] = hh;
        x_lo[n * 264 + 128 + j] = f2b(sv - b2f(hh));
    }
    __syncthreads();

    // ---- phase 4: layer 1 (K=256) -> h
    {
        f32x4 acc1 = (f32x4){0.f, 0.f, 0.f, 0.f};
        #pragma unroll
        for (int t = 0; t < 8; t++) {
            bf16x8 aH = *(const bf16x8*)&x_hi[arow * 264 + t * 32 + kg * 8];
            bf16x8 aL = *(const bf16x8*)&x_lo[arow * 264 + t * 32 + kg * 8];
            bf16x8 bH = *(const bf16x8*)&u1t[(size_t)jw * 256 + t * 32 + kg * 8];
            bf16x8 bL = *(const bf16x8*)&u1t[(size_t)2 * D * D + (size_t)jw * 256 + t * 32 + kg * 8];
            MFMA3(acc1, aH, aL, bH, bL)
        }
        float bias = ub1[jw];
        #pragma unroll
        for (int r = 0; r < 4; r++) {
            int n = kg * 4 + r;
            float hv = silu_f(acc1[r] + bias);
            ushort hh = f2b(hv);
            h_hi[n * 136 + jw] = hh;
            h_lo[n * 136 + jw] = f2b(hv - b2f(hh));
        }
    }
    __syncthreads();

    // ---- phase 5: layer 2 (N=384, 3 tiles per wave) -> a_out
    f32x4 acc2[3];
    #pragma unroll
    for (int q = 0; q < 3; q++) acc2[q] = (f32x4){0.f, 0.f, 0.f, 0.f};
    #pragma unroll
    for (int t = 0; t < 4; t++) {
        bf16x8 aH = *(const bf16x8*)&h_hi[arow * 136 + t * 32 + kg * 8];
        bf16x8 aL = *(const bf16x8*)&h_lo[arow * 136 + t * 32 + kg * 8];
        #pragma unroll
        for (int q = 0; q < 3; q++) {
            int j = (wave * 3 + q) * 16 + arow;
            bf16x8 bH = *(const bf16x8*)&u2t[(size_t)j * 128 + t * 32 + kg * 8];
            bf16x8 bL = *(const bf16x8*)&u2t[(size_t)D3 * D + (size_t)j * 128 + t * 32 + kg * 8];
            MFMA3(acc2[q], aH, aL, bH, bL)
        }
    }
    __syncthreads();   // x/h reads done; a_out may overwrite
    #pragma unroll
    for (int q = 0; q < 3; q++) {
        int j = (wave * 3 + q) * 16 + arow;
        float bias = ub2[j];
        #pragma unroll
        for (int r = 0; r < 4; r++)
            a_out[(kg * 4 + r) * 396 + j] = acc2[q][r] + bias;
    }
    __syncthreads();

    // ---- epilogue (coalesced)
    float snew_reg[4];
    #pragma unroll
    for (int it = 0; it < 4; it++) {
        int t8 = it * 512 + tid;
        int n = t8 >> 7, j = t8 & 127;
        float a1 = a_out[n * 396 + 128 + j];
        float a2 = a_out[n * 396 + 256 + j];
        size_t sidx = (size_t)(n0 + n) * D + j;
        float snew = s[sidx] + a2 + UV_lds[n * 132 + j] * a1;
        if (FUSE) {
            float a0 = a_out[n * 396 + j];
            s[sidx] = snew;
            snew_reg[it] = snew;
            ushort* pvp = pv + ((size_t)(n0 + n) * 128 + j) * 6;
            #pragma unroll
            for (int i = 0; i < 3; i++) {
                size_t idx = ((size_t)(n0 + n) * 3 + i) * D + j;
                float vf = v[idx] + b2f(U_lds[(i * 16 + n) * 136 + j]) * a0;
                v[idx] = vf;
                pvp[3 + i] = f2b(vf);
            }
        } else {
            int gn = gi[n0 + n];
            atomicAdd(&g[(size_t)gn * D + j], snew);
        }
    }

    if (!FUSE) return;

    // ---- fused phi for next round: pv[slot 0..2] = phi(s_new)
    __syncthreads();
    #pragma unroll
    for (int it = 0; it < 4; it++) {
        int t8 = it * 512 + tid;
        int n = t8 >> 7, j = t8 & 127;
        float sv = snew_reg[it];
        ushort hh = f2b(sv);
        x_hi[n * 264 + j] = hh;
        x_lo[n * 264 + j] = f2b(sv - b2f(hh));
    }
    __syncthreads();

    {
        f32x4 accp = (f32x4){0.f, 0.f, 0.f, 0.f};
        #pragma unroll
        for (int t = 0; t < 4; t++) {
            bf16x8 aH = *(const bf16x8*)&x_hi[arow * 264 + t * 32 + kg * 8];
            bf16x8 aL = *(const bf16x8*)&x_lo[arow * 264 + t * 32 + kg * 8];
            bf16x8 bH = *(const bf16x8*)&w1th[(size_t)jw * 128 + t * 32 + kg * 8];
            bf16x8 bL = *(const bf16x8*)&w1tl[(size_t)jw * 128 + t * 32 + kg * 8];
            MFMA3(accp, aH, aL, bH, bL)
        }
        __syncthreads();
        float bias = pb1[jw];
        #pragma unroll
        for (int r = 0; r < 4; r++) {
            int n = kg * 4 + r;
            float hv = silu_f(accp[r] + bias);
            ushort hh = f2b(hv);
            h_hi[n * 136 + jw] = hh;
            h_lo[n * 136 + jw] = f2b(hv - b2f(hh));
        }
    }
    __syncthreads();

    {
        f32x4 accq[3];
        #pragma unroll
        for (int q = 0; q < 3; q++) accq[q] = (f32x4){0.f, 0.f, 0.f, 0.f};
        #pragma unroll
        for (int t = 0; t < 4; t++) {
            bf16x8 aH = *(const bf16x8*)&h_hi[arow * 136 + t * 32 + kg * 8];
            bf16x8 aL = *(const bf16x8*)&h_lo[arow * 136 + t * 32 + kg * 8];
            #pragma unroll
            for (int q = 0; q < 3; q++) {
                int j = (wave * 3 + q) * 16 + arow;
                bf16x8 bH = *(const bf16x8*)&w2th[(size_t)j * 128 + t * 32 + kg * 8];
                bf16x8 bL = *(const bf16x8*)&w2tl[(size_t)j * 128 + t * 32 + kg * 8];
                MFMA3(accq[q], aH, aL, bH, bL)
            }
        }
        #pragma unroll
        for (int q = 0; q < 3; q++) {
            int j = (wave * 3 + q) * 16 + arow;
            float bias = pb2[j];
            int seg = j >> 7;
            int ch  = j & 127;
            #pragma unroll
            for (int r = 0; r < 4; r++) {
                pv[((size_t)(n0 + kg * 4 + r) * 128 + ch) * 6 + seg] = f2b(accq[q][r] + bias);
            }
        }
    }
}

// ---------------------------------------------------------------- readout
__global__ __launch_bounds__(128) void out_mlp(
    const float* __restrict__ g,
    const float* __restrict__ w1, const float* __restrict__ b1,
    const float* __restrict__ w2, const float* __restrict__ b2,
    float* __restrict__ out)
{
    __shared__ float gl[D];
    __shared__ float red[2];
    int j = threadIdx.x;
    int gr = blockIdx.x;
    gl[j] = g[gr * D + j];
    __syncthreads();
    float acc = b1[j];
    for (int k = 0; k < D; k++) acc += gl[k] * w1[k * D + j];
    float h = silu_f(acc) * w2[j];
    #pragma unroll
    for (int off = 32; off >= 1; off >>= 1) h += __shfl_down(h, off);
    if ((j & 63) == 0) red[j >> 6] = h;
    __syncthreads();
    if (j == 0) out[gr] = red[0] + red[1] + b2[0];
}

// ================================================================ launch
extern "C" void kernel_launch(void* const* d_in, const int* in_sizes, int n_in,
                              void* d_out, int out_size, void* d_ws, size_t ws_size,
                              hipStream_t stream)
{
    const int*   edge_src   = (const int*)  d_in[0];
    const int*   edge_dst   = (const int*)  d_in[1];
    const float* edge_vec   = (const float*)d_in[2];
    const int*   atom_types = (const int*)  d_in[3];
    const int*   node_gi    = (const int*)  d_in[4];
    const float* embedding  = (const float*)d_in[5];
    const float* phi_w1     = (const float*)d_in[6];
    const float* phi_b1     = (const float*)d_in[7];
    const float* phi_w2     = (const float*)d_in[8];
    const float* phi_b2     = (const float*)d_in[9];
    const float* filt_w     = (const float*)d_in[10];
    const float* filt_b     = (const float*)d_in[11];
    const float* upd_w1     = (const float*)d_in[12];
    const float* upd_b1     = (const float*)d_in[13];
    const float* upd_w2     = (const float*)d_in[14];
    const float* upd_b2     = (const float*)d_in[15];
    const float* U_w        = (const float*)d_in[16];
    const float* V_w        = (const float*)d_in[17];
    const float* out_w1     = (const float*)d_in[18];
    const float* out_b1     = (const float*)d_in[19];
    const float* out_w2     = (const float*)d_in[20];
    const float* out_b2     = (const float*)d_in[21];

    float* ws = (float*)d_ws;
    size_t o = 0;
    float* s_a   = ws + o; o += (size_t)NN * D;
    float* s_b   = ws + o; o += (size_t)NN * D;
    float* v_a   = ws + o; o += (size_t)NN * 3 * D;
    float* v_b   = ws + o; o += (size_t)NN * 3 * D;
    float* pv_f  = ws + o; o += (size_t)NN * 384;             // pv: [n][128][6] bf16
    float* rbf_f = ws + o; o += (size_t)NE * RBF_ROW;         // fp32, CSR order
    float* geo   = ws + o; o += (size_t)NE * 4;               // CSR order
    float* g     = ws + o; o += (size_t)NG * D;
    float* w1t_f = ws + o; o += (size_t)D * D;                // phi w1 hi+lo
    float* w2t_f = ws + o; o += (size_t)D3 * D;               // phi w2 hi+lo
    float* uwt_f = ws + o; o += (size_t)D * D;                // Uw^T hi+lo
    float* vwt_f = ws + o; o += (size_t)D * D;                // Vw^T hi+lo
    float* u1t_f = ws + o; o += (size_t)2 * D * D;            // upd_w1^T hi+lo
    float* u2t_f = ws + o; o += (size_t)D3 * D;               // upd_w2^T hi+lo
    float* ptab_f= ws + o; o += (size_t)10 * D;               // round-0 phi table
    int* deg     = (int*)(ws + o); o += NN;
    int* offs    = (int*)(ws + o); o += NN + 1;
    int* cursor  = (int*)(ws + o); o += NN;
    int* perm    = (int*)(ws + o); o += NN;
    int* bpos    = (int*)(ws + o); o += 64;
    int* src_csr = (int*)(ws + o); o += NE;
    int* styp_csr= (int*)(ws + o); o += NE;

    ushort* pv    = (ushort*)pv_f;
    ushort* w1th  = (ushort*)w1t_f;
    ushort* w1tl  = w1th + (size_t)D * D;
    ushort* w2th  = (ushort*)w2t_f;
    ushort* w2tl  = w2th + (size_t)D3 * D;
    ushort* uwt   = (ushort*)uwt_f;
    ushort* vwt   = (ushort*)vwt_f;
    ushort* u1t   = (ushort*)u1t_f;
    ushort* u2t   = (ushort*)u2t_f;
    uint*   ptab  = (uint*)ptab_f;

    mega_init<<<512, 256, 0, stream>>>(g, deg, phi_w1, phi_w2,
                                       w1th, w1tl, w2th, w2tl,
                                       U_w, V_w, upd_w1, upd_w2,
                                       uwt, vwt, u1t, u2t);
    csr_count<<<(NE + 255) / 256, 256, 0, stream>>>(edge_dst, deg);
    scan_all<<<1, 1024, 0, stream>>>(deg, offs, cursor, bpos);
    geom_scatter<<<(NE + 255) / 256, 256, 0, stream>>>(edge_vec, edge_dst, edge_src,
                                                       atom_types, cursor,
                                                       rbf_f, (float4*)geo,
                                                       src_csr, styp_csr,
                                                       deg, bpos, perm);
    phi10<<<10, 128, 0, stream>>>(embedding, phi_w1, phi_b1, phi_w2, phi_b2, ptab);

    // round 0 (v = 0 specialization)
    node_gather_r0<<<NN / 4, 512, 0, stream>>>(offs, perm, styp_csr,
                                               atom_types, embedding, ptab,
                                               rbf_f, (const float4*)geo,
                                               filt_w, filt_b, s_b, v_b);
    node_vupd_mfma<true><<<NN / 16, 512, 0, stream>>>(s_b, v_b, pv, node_gi, g,
                                                      uwt, vwt, u1t, u2t,
                                                      upd_b1, upd_b2,
                                                      w1th, w1tl, phi_b1,
                                                      w2th, w2tl, phi_b2);
    // round 1
    node_gather<<<NN / 4, 512, 0, stream>>>(offs, perm, src_csr, pv,
                                            s_b, v_b, rbf_f,
                                            (const float4*)geo, filt_w, filt_b,
                                            s_a, v_a);
    node_vupd_mfma<false><<<NN / 16, 512, 0, stream>>>(s_a, v_a, pv, node_gi, g,
                                                       uwt, vwt, u1t, u2t,
                                                       upd_b1, upd_b2,
                                                       w1th, w1tl, phi_b1,
                                                       w2th, w2tl, phi_b2);

    out_mlp<<<NG, 128, 0, stream>>>(g, out_w1, out_b1, out_w2, out_b2, (float*)d_out);
}

// Round 23
// 574.342 us; speedup vs baseline: 1.0440x; 1.0296x over previous
//
#include <hip/hip_runtime.h>

#define NN 20000
#define NE 320000
#define NG 64
#define D 128
#define D3 384
#define NRBF 20
#define RBF_ROW 24       // fp32 per rbf row -> 96B, 16B-aligned
#define PI_F 3.14159265358979323846f
#define RCUT 10.0f

typedef unsigned int uint;
typedef unsigned short ushort;
typedef __attribute__((ext_vector_type(8))) short bf16x8;
typedef __attribute__((ext_vector_type(4))) float f32x4;
typedef __attribute__((ext_vector_type(2))) float v2f;

__device__ __forceinline__ float silu_f(float x) {
    return x / (1.0f + __expf(-x));
}
__device__ __forceinline__ float b2f(ushort u) {
    return __uint_as_float(((uint)u) << 16);
}
__device__ __forceinline__ ushort f2b(float f) {
    uint u = __float_as_uint(f);
    u = u + 0x7fffu + ((u >> 16) & 1u);
    return (ushort)(u >> 16);
}
__device__ __forceinline__ float plo(uint u) { return __uint_as_float(u << 16); }
__device__ __forceinline__ float phi_(uint u) { return __uint_as_float(u & 0xffff0000u); }

#define MFMA3(acc, aH, aL, bH, bL)                                          \
    acc = __builtin_amdgcn_mfma_f32_16x16x32_bf16(aL, bH, acc, 0, 0, 0);    \
    acc = __builtin_amdgcn_mfma_f32_16x16x32_bf16(aH, bL, acc, 0, 0, 0);    \
    acc = __builtin_amdgcn_mfma_f32_16x16x32_bf16(aH, bH, acc, 0, 0, 0);

// ---------------------------------------------------------------- mega init (+ csr_count fused)
__global__ __launch_bounds__(256) void mega_init(
    float* __restrict__ g, int* __restrict__ deg,
    const int* __restrict__ dst,
    const float* __restrict__ pw1, const float* __restrict__ pw2,
    ushort* __restrict__ w1th, ushort* __restrict__ w1tl,
    ushort* __restrict__ w2th, ushort* __restrict__ w2tl,
    const float* __restrict__ Uw, const float* __restrict__ Vw,
    const float* __restrict__ uw1, const float* __restrict__ uw2,
    ushort* __restrict__ uwt, ushort* __restrict__ vwt,
    ushort* __restrict__ u1t, ushort* __restrict__ u2t)
{
    int stride = gridDim.x * blockDim.x;
    int idx0 = blockIdx.x * blockDim.x + threadIdx.x;
    for (int i = idx0; i < NG * D; i += stride) g[i] = 0.f;
    for (int i = idx0; i < NN; i += stride) deg[i] = 0;
    for (int i = idx0; i < D * D; i += stride) {
        int j = i >> 7, k = i & 127;
        float x = pw1[k * D + j]; ushort h = f2b(x);
        w1th[i] = h; w1tl[i] = f2b(x - b2f(h));
        float a = Uw[k * D + j]; ushort ha = f2b(a);
        uwt[i] = ha; uwt[D * D + i] = f2b(a - b2f(ha));
        float b = Vw[k * D + j]; ushort hb = f2b(b);
        vwt[i] = hb; vwt[D * D + i] = f2b(b - b2f(hb));
    }
    for (int i = idx0; i < D3 * D; i += stride) {
        int j = i >> 7, k = i & 127;
        float x = pw2[k * D3 + j]; ushort h = f2b(x);
        w2th[i] = h; w2tl[i] = f2b(x - b2f(h));
        float y = uw2[k * D3 + j]; ushort hy = f2b(y);
        u2t[i] = hy; u2t[D3 * D + i] = f2b(y - b2f(hy));
    }
    for (int i = idx0; i < 2 * D * D; i += stride) {
        int j = i >> 8, k = i & 255;
        float x = uw1[k * D + j]; ushort h = f2b(x);
        u1t[i] = h; u1t[2 * D * D + i] = f2b(x - b2f(h));
    }
    // fused csr_count (deg zeroed above by the same grid earlier iterations;
    // safe because each thread zeroes deg[i] for i in its stride set before
    // any thread reaches this loop? NOT guaranteed across blocks -> use a
    // separate grid-stride pass ordering hazard. Instead: zero via atomicExch
    // is overkill; keep count in a SECOND kernel-wide pass is wrong too.
    // Correct approach: deg zeroing happens in the loop above, but another
    // block may increment deg[i] before block owning i zeroes it.
    // => do NOT fuse blindly; use a grid-wide split: counting is deferred
    //    to the tail loop below ONLY after cooperative ordering is impossible.
    // Resolution: deg is zeroed by loop 2; to be safe we count into deg here
    // only if every deg element is zeroed first. Since both loops use the
    // same grid-stride pattern but different bounds, ordering is NOT safe.
    // Therefore counting stays in this kernel but writes to deg via atomic
    // AFTER a device-scope handshake is impossible without coop launch.
    // -> keep correctness: no-op here (see csr_count kernel below).
}

// ---------------------------------------------------------------- CSR count (kept separate — see note in mega_init)
__global__ __launch_bounds__(256) void csr_count(
    const int* __restrict__ dst, int* __restrict__ deg)
{
    int e = blockIdx.x * blockDim.x + threadIdx.x;
    if (e < NE) atomicAdd(&deg[dst[e]], 1);
}

// ---------------------------------------------------------------- scan (CSR offsets + degree-bucket positions)
__global__ __launch_bounds__(1024) void scan_all(
    const int* __restrict__ deg, int* __restrict__ offs,
    int* __restrict__ cursor, int* __restrict__ bpos)
{
    __shared__ int part[1024];
    __shared__ int bc[64];
    int t = threadIdx.x;
    if (t < 64) bc[t] = 0;
    __syncthreads();
    const int per = (NN + 1023) / 1024;  // 20
    int base = t * per;
    int sum = 0;
    for (int i = 0; i < per; i++) {
        int idx = base + i;
        if (idx < NN) {
            int dg = deg[idx];
            sum += dg;
            int b = dg > 63 ? 63 : dg;
            atomicAdd(&bc[b], 1);
        }
    }
    part[t] = sum;
    __syncthreads();
    for (int off = 1; off < 1024; off <<= 1) {
        int vv = (t >= off) ? part[t - off] : 0;
        __syncthreads();
        part[t] += vv;
        __syncthreads();
    }
    int run = part[t] - sum;
    for (int i = 0; i < per; i++) {
        int idx = base + i;
        if (idx < NN) {
            offs[idx] = run;
            cursor[idx] = run;
            run += deg[idx];
        }
    }
    if (t == 1023) offs[NN] = run;
    __syncthreads();
    if (t == 0) {
        int r2 = 0;
        for (int b = 63; b >= 0; b--) { bpos[b] = r2; r2 += bc[b]; }  // descending degree
    }
}

// ---------------------------------------------------------------- geometry + CSR scatter
// rbf via Chebyshev recurrence: sin((k+1)x) = 2cos(x)·sin(kx) − sin((k−1)x)
// (one sincos + 19 FMA pairs instead of 20 sinf; rel err ~1e-6)
__global__ __launch_bounds__(256) void geom_scatter(
    const float* __restrict__ evec, const int* __restrict__ dst,
    const int* __restrict__ srcv, const int* __restrict__ atype,
    int* __restrict__ cursor,
    float* __restrict__ rbf, float4* __restrict__ geo,
    int* __restrict__ src_csr, int* __restrict__ styp_csr,
    const int* __restrict__ deg, int* __restrict__ bpos, int* __restrict__ perm)
{
    int e = blockIdx.x * blockDim.x + threadIdx.x;
    if (e < NE) {
        int p = atomicAdd(&cursor[dst[e]], 1);
        float x = evec[e * 3 + 0], y = evec[e * 3 + 1], z = evec[e * 3 + 2];
        float r = sqrtf(x * x + y * y + z * z);
        float inv = 1.0f / r;
        float f = (r < RCUT) ? 0.5f * (cosf(PI_F * r / RCUT) + 1.0f) : 0.0f;
        float4 gg;
        gg.x = x * inv; gg.y = y * inv; gg.z = z * inv; gg.w = f;
        geo[p] = gg;
        int sn = srcv[e];
        src_csr[p] = sn;
        styp_csr[p] = atype[sn];
        float base = PI_F * r / RCUT;
        float sf = inv * f;
        float s1, c1;
        __sincosf(base, &s1, &c1);
        float c2 = 2.0f * c1;
        float sk_prev = 0.0f;      // sin(0·x)
        float sk = s1;             // sin(1·x)
        float* rp = rbf + (size_t)p * RBF_ROW;
        #pragma unroll
        for (int k = 0; k < NRBF; k++) {
            rp[k] = sk * sf;
            float sk_next = c2 * sk - sk_prev;
            sk_prev = sk;
            sk = sk_next;
        }
    }
    if (e < NN) {
        int b = deg[e]; if (b > 63) b = 63;
        int p = atomicAdd(&bpos[b], 1);
        perm[p] = e;
    }
}

// ---------------------------------------------------------------- phi table (round 0)
__global__ __launch_bounds__(128) void phi10(
    const float* __restrict__ emb,
    const float* __restrict__ w1, const float* __restrict__ b1,
    const float* __restrict__ w2, const float* __restrict__ b2,
    uint* __restrict__ ptab)
{
    __shared__ float el[D];
    __shared__ float hl[D];
    int t = blockIdx.x, j = threadIdx.x;
    el[j] = emb[t * D + j];
    __syncthreads();
    float acc = b1[j];
    for (int k = 0; k < D; k++) acc += el[k] * w1[k * D + j];
    hl[j] = silu_f(acc);
    __syncthreads();
    float a1 = b2[D + j], a2 = b2[2 * D + j];
    for (int k = 0; k < D; k++) {
        float h = hl[k];
        a1 += h * w2[k * D3 + D + j];
        a2 += h * w2[k * D3 + 2 * D + j];
    }
    ptab[t * D + j] = (uint)f2b(a1) | ((uint)f2b(a2) << 16);
}

// ---------------------------------------------------------------- node gather round 0 (v=0; CSR-sequential; R17 verified)
// waves_per_eu(4,4): REQUIRED — weight-resident design spills at any higher
// wave target. Verified: R4 (290MB scratch), R9 (200MB), R19 (160MB @ (6,6)).
__global__ __launch_bounds__(512)
__attribute__((amdgpu_waves_per_eu(4, 4)))
void node_gather_r0(
    const int* __restrict__ offs,
    const int* __restrict__ perm, const int* __restrict__ styp_csr,
    const int* __restrict__ atype, const float* __restrict__ emb,
    const uint* __restrict__ ptab,
    const float* __restrict__ rbf, const float4* __restrict__ geo,
    const float* __restrict__ filt_w, const float* __restrict__ filt_b,
    float* __restrict__ s_new, float* __restrict__ v_new)
{
    int wave = threadIdx.x >> 6;
    int lane = threadIdx.x & 63;
    int widx = blockIdx.x * 4 + (wave >> 1);
    if (widx >= NN) return;
    int node = __builtin_amdgcn_readfirstlane(perm[widx]);
    int half = wave & 1;
    int d = half * 64 + lane;

    v2f wr1v[10], wr2v[10];
    #pragma unroll
    for (int m = 0; m < 10; m++) {
        wr1v[m] = (v2f){filt_w[(2 * m) * D3 + D + d],     filt_w[(2 * m + 1) * D3 + D + d]};
        wr2v[m] = (v2f){filt_w[(2 * m) * D3 + 2 * D + d], filt_w[(2 * m + 1) * D3 + 2 * D + d]};
    }
    float fb1 = filt_b[D + d], fb2 = filt_b[2 * D + d];
    int e0 = __builtin_amdgcn_readfirstlane(offs[node]);
    int e1 = __builtin_amdgcn_readfirstlane(offs[node + 1]);

    float acc_s = 0.f, av0 = 0.f, av1 = 0.f, av2 = 0.f;

    for (int i = e0; i < e1; i += 2) {
        bool hb = (i + 1 < e1);
        int ib = hb ? i + 1 : i;
        float mb = hb ? 1.0f : 0.0f;
        int ta = __builtin_amdgcn_readfirstlane(styp_csr[i]);
        int tb = __builtin_amdgcn_readfirstlane(styp_csr[ib]);
        float4 ga = geo[i];
        float4 gb = geo[ib];
        const float* rpa = rbf + (size_t)i * RBF_ROW;
        const float* rpb = rbf + (size_t)ib * RBF_ROW;
        uint pka = ptab[ta * D + d];
        uint pkb = ptab[tb * D + d];

        v2f Wa1v = {0.f, 0.f}, Wa2v = {0.f, 0.f};
        v2f Wb1v = {0.f, 0.f}, Wb2v = {0.f, 0.f};
        #pragma unroll
        for (int m = 0; m < 10; m++) {
            float2 ra2 = *(const float2*)(rpa + 2 * m);
            float2 rb2 = *(const float2*)(rpb + 2 * m);
            v2f rav = {ra2.x, ra2.y};
            v2f rbv = {rb2.x, rb2.y};
            Wa1v += rav * wr1v[m]; Wa2v += rav * wr2v[m];
            Wb1v += rbv * wr1v[m]; Wb2v += rbv * wr2v[m];
        }
        float Wa1 = Wa1v.x + Wa1v.y + ga.w * fb1;
        float Wa2 = Wa2v.x + Wa2v.y + ga.w * fb2;
        float Wb1 = Wb1v.x + Wb1v.y + gb.w * fb1;
        float Wb2 = Wb2v.x + Wb2v.y + gb.w * fb2;

        float pa1 = plo(pka), pa2 = phi_(pka);
        float pb1 = plo(pkb), pb2 = phi_(pkb);

        float m2a = pa1 * Wa1, m3a = pa2 * Wa2;
        float m2b = pb1 * Wb1 * mb, m3b = pb2 * Wb2 * mb;
        acc_s += m2a + m2b;
        av0 += ga.x * m3a + gb.x * m3b;
        av1 += ga.y * m3a + gb.y * m3b;
        av2 += ga.z * m3a + gb.z * m3b;
    }

    int tn = __builtin_amdgcn_readfirstlane(atype[node]);
    s_new[node * D + d] = emb[tn * D + d] + acc_s;
    v_new[(node * 3 + 0) * D + d] = av0;
    v_new[(node * 3 + 1) * D + d] = av1;
    v_new[(node * 3 + 2) * D + d] = av2;
}

// ---------------------------------------------------------------- node gather (round 1; CSR-sequential + pv prefetch; R21)
__global__ __launch_bounds__(512)
__attribute__((amdgpu_waves_per_eu(4, 4)))
void node_gather(
    const int* __restrict__ offs,
    const int* __restrict__ perm, const int* __restrict__ src_csr,
    const ushort* __restrict__ pv,
    const float* __restrict__ s_old, const float* __restrict__ v_old,
    const float* __restrict__ rbf, const float4* __restrict__ geo,
    const float* __restrict__ filt_w, const float* __restrict__ filt_b,
    float* __restrict__ s_new, float* __restrict__ v_new)
{
    int wave = threadIdx.x >> 6;
    int lane = threadIdx.x & 63;
    int widx = blockIdx.x * 4 + (wave >> 1);
    if (widx >= NN) return;
    int node = __builtin_amdgcn_readfirstlane(perm[widx]);
    int half = wave & 1;
    int d = half * 64 + lane;

    v2f wr0v[10], wr1v[10], wr2v[10];
    #pragma unroll
    for (int m = 0; m < 10; m++) {
        wr0v[m] = (v2f){filt_w[(2 * m) * D3 + d],         filt_w[(2 * m + 1) * D3 + d]};
        wr1v[m] = (v2f){filt_w[(2 * m) * D3 + D + d],     filt_w[(2 * m + 1) * D3 + D + d]};
        wr2v[m] = (v2f){filt_w[(2 * m) * D3 + 2 * D + d], filt_w[(2 * m + 1) * D3 + 2 * D + d]};
    }
    float fb0 = filt_b[d], fb1 = filt_b[D + d], fb2 = filt_b[2 * D + d];
    int e0 = __builtin_amdgcn_readfirstlane(offs[node]);
    int e1 = __builtin_amdgcn_readfirstlane(offs[node + 1]);

    float acc_s = 0.f, av0 = 0.f, av1 = 0.f, av2 = 0.f;
    size_t doff = (size_t)d * 6;

    uint3 pka = {0, 0, 0}, pkb = {0, 0, 0};
    if (e0 < e1) {
        int ib0 = (e0 + 1 < e1) ? e0 + 1 : e0;
        int sa0 = __builtin_amdgcn_readfirstlane(src_csr[e0]);
        int sb0 = __builtin_amdgcn_readfirstlane(src_csr[ib0]);
        pka = *(const uint3*)(pv + (size_t)sa0 * 768 + doff);
        pkb = *(const uint3*)(pv + (size_t)sb0 * 768 + doff);
    }

    for (int i = e0; i < e1; i += 2) {
        bool hb = (i + 1 < e1);
        int ib = hb ? i + 1 : i;
        float mb = hb ? 1.0f : 0.0f;
        float4 ga = geo[i];
        float4 gb = geo[ib];
        const float* rpa = rbf + (size_t)i * RBF_ROW;
        const float* rpb = rbf + (size_t)ib * RBF_ROW;

        uint3 pka_n = pka, pkb_n = pkb;
        int inext = i + 2;
        if (inext < e1) {
            int ibn = (inext + 1 < e1) ? inext + 1 : inext;
            int sa_n = __builtin_amdgcn_readfirstlane(src_csr[inext]);
            int sb_n = __builtin_amdgcn_readfirstlane(src_csr[ibn]);
            pka_n = *(const uint3*)(pv + (size_t)sa_n * 768 + doff);
            pkb_n = *(const uint3*)(pv + (size_t)sb_n * 768 + doff);
        }

        v2f Wa0v = {0.f, 0.f}, Wa1v = {0.f, 0.f}, Wa2v = {0.f, 0.f};
        v2f Wb0v = {0.f, 0.f}, Wb1v = {0.f, 0.f}, Wb2v = {0.f, 0.f};
        #pragma unroll
        for (int m = 0; m < 10; m++) {
            float2 ra2 = *(const float2*)(rpa + 2 * m);
            float2 rb2 = *(const float2*)(rpb + 2 * m);
            v2f rav = {ra2.x, ra2.y};
            v2f rbv = {rb2.x, rb2.y};
            Wa0v += rav * wr0v[m]; Wa1v += rav * wr1v[m]; Wa2v += rav * wr2v[m];
            Wb0v += rbv * wr0v[m]; Wb1v += rbv * wr1v[m]; Wb2v += rbv * wr2v[m];
        }
        float Wa0 = Wa0v.x + Wa0v.y + ga.w * fb0;
        float Wa1 = Wa1v.x + Wa1v.y + ga.w * fb1;
        float Wa2 = Wa2v.x + Wa2v.y + ga.w * fb2;
        float Wb0 = Wb0v.x + Wb0v.y + gb.w * fb0;
        float Wb1 = Wb1v.x + Wb1v.y + gb.w * fb1;
        float Wb2 = Wb2v.x + Wb2v.y + gb.w * fb2;

        float pa0 = plo(pka.x), pa1 = phi_(pka.x), pa2 = plo(pka.y);
        float va0 = phi_(pka.y), va1 = plo(pka.z), va2 = phi_(pka.z);
        float pb0 = plo(pkb.x), pb1 = phi_(pkb.x), pb2 = plo(pkb.y);
        float vb0 = phi_(pkb.y), vb1 = plo(pkb.z), vb2 = phi_(pkb.z);

        float m1a = pa0 * Wa0, m2a = pa1 * Wa1, m3a = pa2 * Wa2;
        float m1b = pb0 * Wb0 * mb, m2b = pb1 * Wb1 * mb, m3b = pb2 * Wb2 * mb;
        acc_s += m2a + m2b;
        av0 += va0 * m1a + ga.x * m3a + vb0 * m1b + gb.x * m3b;
        av1 += va1 * m1a + ga.y * m3a + vb1 * m1b + gb.y * m3b;
        av2 += va2 * m1a + ga.z * m3a + vb2 * m1b + gb.z * m3b;

        pka = pka_n; pkb = pkb_n;
    }

    s_new[node * D + d] = s_old[node * D + d] + acc_s;
    v_new[(node * 3 + 0) * D + d] = v_old[(node * 3 + 0) * D + d] + av0;
    v_new[(node * 3 + 1) * D + d] = v_old[(node * 3 + 1) * D + d] + av1;
    v_new[(node * 3 + 2) * D + d] = v_old[(node * 3 + 2) * D + d] + av2;
}

// ---------------------------------------------------------------- fused update via MFMA bf16x3 (R18 verified)
template<bool FUSE>
__global__ __launch_bounds__(512) void node_vupd_mfma(
    float* __restrict__ s, float* __restrict__ v, ushort* __restrict__ pv,
    const int* __restrict__ gi, float* __restrict__ g,
    const ushort* __restrict__ uwt, const ushort* __restrict__ vwt,
    const ushort* __restrict__ u1t, const ushort* __restrict__ u2t,
    const float* __restrict__ ub1, const float* __restrict__ ub2,
    const ushort* __restrict__ w1th, const ushort* __restrict__ w1tl,
    const float* __restrict__ pb1,
    const ushort* __restrict__ w2th, const ushort* __restrict__ w2tl,
    const float* __restrict__ pb2)
{
    constexpr int U_BYTES = FUSE ? 13056 : 0;        // [48][136] bf16 (FUSE only)
    constexpr int UV_OFF  = U_BYTES;
    constexpr int B_OFF   = UV_OFF + 8448;           // UV: [16][132] f32
    constexpr int SMEM_SZ = B_OFF + 26112;           // region B (a/x/h or a_out[16][396])
    __shared__ __align__(16) char smem[SMEM_SZ];
    ushort* U_lds  = (ushort*)(smem);
    float*  UV_lds = (float*)(smem + UV_OFF);
    ushort* a_hi   = (ushort*)(smem + B_OFF);        // [48][136]
    ushort* a_lo   = a_hi + 48 * 136;
    ushort* x_hi   = (ushort*)(smem + B_OFF);        // [16][264]
    ushort* x_lo   = x_hi + 16 * 264;
    ushort* h_hi   = x_lo + 16 * 264;                // [16][136]
    ushort* h_lo   = h_hi + 16 * 136;
    float*  a_out  = (float*)(smem + B_OFF);         // [16][396] padded

    int tid = threadIdx.x;
    int wave = tid >> 6, lane = tid & 63;
    int arow = lane & 15, kg = lane >> 4;
    int n0 = blockIdx.x * 16;
    int jw = wave * 16 + arow;                       // this wave's j column

    // ---- phase 1: stage v (bf16 hi/lo)
    #pragma unroll
    for (int it = 0; it < 3; it++) {
        int f4 = it * 512 + tid;
        int row = f4 >> 5;
        int c4 = (f4 & 31) * 4;
        int i = row >> 4, n = row & 15;
        float4 vv = *(const float4*)&v[((size_t)(n0 + n) * 3 + i) * D + c4];
        ushort h0 = f2b(vv.x), h1 = f2b(vv.y), h2 = f2b(vv.z), h3 = f2b(vv.w);
        ushort l0 = f2b(vv.x - b2f(h0)), l1 = f2b(vv.y - b2f(h1));
        ushort l2 = f2b(vv.z - b2f(h2)), l3 = f2b(vv.w - b2f(h3));
        uint2 ph; ph.x = (uint)h0 | ((uint)h1 << 16); ph.y = (uint)h2 | ((uint)h3 << 16);
        uint2 pl; pl.x = (uint)l0 | ((uint)l1 << 16); pl.y = (uint)l2 | ((uint)l3 << 16);
        *(uint2*)&a_hi[row * 136 + c4] = ph;
        *(uint2*)&a_lo[row * 136 + c4] = pl;
    }
    __syncthreads();

    // ---- phase 2: U = v@Uw, Vp = v@Vw (one j-tile per wave)
    f32x4 accU[3], accVp[3];
    #pragma unroll
    for (int i = 0; i < 3; i++) {
        accU[i] = (f32x4){0.f, 0.f, 0.f, 0.f};
        accVp[i] = (f32x4){0.f, 0.f, 0.f, 0.f};
    }
    #pragma unroll
    for (int i = 0; i < 3; i++) {
        #pragma unroll
        for (int t = 0; t < 4; t++) {
            bf16x8 aH = *(const bf16x8*)&a_hi[(i * 16 + arow) * 136 + t * 32 + kg * 8];
            bf16x8 aL = *(const bf16x8*)&a_lo[(i * 16 + arow) * 136 + t * 32 + kg * 8];
            bf16x8 bH = *(const bf16x8*)&uwt[(size_t)jw * 128 + t * 32 + kg * 8];
            bf16x8 bL = *(const bf16x8*)&uwt[(size_t)D * D + (size_t)jw * 128 + t * 32 + kg * 8];
            MFMA3(accU[i], aH, aL, bH, bL)
            bf16x8 cH = *(const bf16x8*)&vwt[(size_t)jw * 128 + t * 32 + kg * 8];
            bf16x8 cL = *(const bf16x8*)&vwt[(size_t)D * D + (size_t)jw * 128 + t * 32 + kg * 8];
            MFMA3(accVp[i], aH, aL, cH, cL)
        }
    }
    __syncthreads();   // a reads done; region B reusable as x

    // ---- phase 3: U->LDS (FUSE), UV->LDS, Vn->x; stage s->x[:,128+]
    #pragma unroll
    for (int r = 0; r < 4; r++) {
        int n = kg * 4 + r;
        if (FUSE) {
            #pragma unroll
            for (int i = 0; i < 3; i++)
                U_lds[(i * 16 + n) * 136 + jw] = f2b(accU[i][r]);
        }
        float uv = accU[0][r] * accVp[0][r]
                 + accU[1][r] * accVp[1][r]
                 + accU[2][r] * accVp[2][r];
        float nn = accVp[0][r] * accVp[0][r]
                 + accVp[1][r] * accVp[1][r]
                 + accVp[2][r] * accVp[2][r];
        UV_lds[n * 132 + jw] = uv;
        float vn = sqrtf(nn);
        ushort hh = f2b(vn);
        x_hi[n * 264 + jw] = hh;
        x_lo[n * 264 + jw] = f2b(vn - b2f(hh));
    }
    #pragma unroll
    for (int it = 0; it < 4; it++) {
        int t8 = it * 512 + tid;
        int n = t8 >> 7, j = t8 & 127;
        float sv = s[(size_t)(n0 + n) * D + j];
        ushort hh = f2b(sv);
        x_hi[n * 264 + 128 + j] = hh;
        x_lo[n * 264 + 128 + j] = f2b(sv - b2f(hh));
    }
    __syncthreads();

    // ---- phase 4: layer 1 (K=256) -> h
    {
        f32x4 acc1 = (f32x4){0.f, 0.f, 0.f, 0.f};
        #pragma unroll
        for (int t = 0; t < 8; t++) {
            bf16x8 aH = *(const bf16x8*)&x_hi[arow * 264 + t * 32 + kg * 8];
            bf16x8 aL = *(const bf16x8*)&x_lo[arow * 264 + t * 32 + kg * 8];
            bf16x8 bH = *(const bf16x8*)&u1t[(size_t)jw * 256 + t * 32 + kg * 8];
            bf16x8 bL = *(const bf16x8*)&u1t[(size_t)2 * D * D + (size_t)jw * 256 + t * 32 + kg * 8];
            MFMA3(acc1, aH, aL, bH, bL)
        }
        float bias = ub1[jw];
        #pragma unroll
        for (int r = 0; r < 4; r++) {
            int n = kg * 4 + r;
            float hv = silu_f(acc1[r] + bias);
            ushort hh = f2b(hv);
            h_hi[n * 136 + jw] = hh;
            h_lo[n * 136 + jw] = f2b(hv - b2f(hh));
        }
    }
    __syncthreads();

    // ---- phase 5: layer 2 (N=384, 3 tiles per wave) -> a_out
    f32x4 acc2[3];
    #pragma unroll
    for (int q = 0; q < 3; q++) acc2[q] = (f32x4){0.f, 0.f, 0.f, 0.f};
    #pragma unroll
    for (int t = 0; t < 4; t++) {
        bf16x8 aH = *(const bf16x8*)&h_hi[arow * 136 + t * 32 + kg * 8];
        bf16x8 aL = *(const bf16x8*)&h_lo[arow * 136 + t * 32 + kg * 8];
        #pragma unroll
        for (int q = 0; q < 3; q++) {
            int j = (wave * 3 + q) * 16 + arow;
            bf16x8 bH = *(const bf16x8*)&u2t[(size_t)j * 128 + t * 32 + kg * 8];
            bf16x8 bL = *(const bf16x8*)&u2t[(size_t)D3 * D + (size_t)j * 128 + t * 32 + kg * 8];
            MFMA3(acc2[q], aH, aL, bH, bL)
        }
    }
    __syncthreads();   // x/h reads done; a_out may overwrite
    #pragma unroll
    for (int q = 0; q < 3; q++) {
        int j = (wave * 3 + q) * 16 + arow;
        float bias = ub2[j];
        #pragma unroll
        for (int r = 0; r < 4; r++)
            a_out[(kg * 4 + r) * 396 + j] = acc2[q][r] + bias;
    }
    __syncthreads();

    // ---- epilogue (coalesced)
    float snew_reg[4];
    #pragma unroll
    for (int it = 0; it < 4; it++) {
        int t8 = it * 512 + tid;
        int n = t8 >> 7, j = t8 & 127;
        float a1 = a_out[n * 396 + 128 + j];
        float a2 = a_out[n * 396 + 256 + j];
        size_t sidx = (size_t)(n0 + n) * D + j;
        float snew = s[sidx] + a2 + UV_lds[n * 132 + j] * a1;
        if (FUSE) {
            float a0 = a_out[n * 396 + j];
            s[sidx] = snew;
            snew_reg[it] = snew;
            ushort* pvp = pv + ((size_t)(n0 + n) * 128 + j) * 6;
            #pragma unroll
            for (int i = 0; i < 3; i++) {
                size_t idx = ((size_t)(n0 + n) * 3 + i) * D + j;
                float vf = v[idx] + b2f(U_lds[(i * 16 + n) * 136 + j]) * a0;
                v[idx] = vf;
                pvp[3 + i] = f2b(vf);
            }
        } else {
            int gn = gi[n0 + n];
            atomicAdd(&g[(size_t)gn * D + j], snew);
        }
    }

    if (!FUSE) return;

    // ---- fused phi for next round: pv[slot 0..2] = phi(s_new)
    __syncthreads();
    #pragma unroll
    for (int it = 0; it < 4; it++) {
        int t8 = it * 512 + tid;
        int n = t8 >> 7, j = t8 & 127;
        float sv = snew_reg[it];
        ushort hh = f2b(sv);
        x_hi[n * 264 + j] = hh;
        x_lo[n * 264 + j] = f2b(sv - b2f(hh));
    }
    __syncthreads();

    {
        f32x4 accp = (f32x4){0.f, 0.f, 0.f, 0.f};
        #pragma unroll
        for (int t = 0; t < 4; t++) {
            bf16x8 aH = *(const bf16x8*)&x_hi[arow * 264 + t * 32 + kg * 8];
            bf16x8 aL = *(const bf16x8*)&x_lo[arow * 264 + t * 32 + kg * 8];
            bf16x8 bH = *(const bf16x8*)&w1th[(size_t)jw * 128 + t * 32 + kg * 8];
            bf16x8 bL = *(const bf16x8*)&w1tl[(size_t)jw * 128 + t * 32 + kg * 8];
            MFMA3(accp, aH, aL, bH, bL)
        }
        __syncthreads();
        float bias = pb1[jw];
        #pragma unroll
        for (int r = 0; r < 4; r++) {
            int n = kg * 4 + r;
            float hv = silu_f(accp[r] + bias);
            ushort hh = f2b(hv);
            h_hi[n * 136 + jw] = hh;
            h_lo[n * 136 + jw] = f2b(hv - b2f(hh));
        }
    }
    __syncthreads();

    {
        f32x4 accq[3];
        #pragma unroll
        for (int q = 0; q < 3; q++) accq[q] = (f32x4){0.f, 0.f, 0.f, 0.f};
        #pragma unroll
        for (int t = 0; t < 4; t++) {
            bf16x8 aH = *(const bf16x8*)&h_hi[arow * 136 + t * 32 + kg * 8];
            bf16x8 aL = *(const bf16x8*)&h_lo[arow * 136 + t * 32 + kg * 8];
            #pragma unroll
            for (int q = 0; q < 3; q++) {
                int j = (wave * 3 + q) * 16 + arow;
                bf16x8 bH = *(const bf16x8*)&w2th[(size_t)j * 128 + t * 32 + kg * 8];
                bf16x8 bL = *(const bf16x8*)&w2tl[(size_t)j * 128 + t * 32 + kg * 8];
                MFMA3(accq[q], aH, aL, bH, bL)
            }
        }
        #pragma unroll
        for (int q = 0; q < 3; q++) {
            int j = (wave * 3 + q) * 16 + arow;
            float bias = pb2[j];
            int seg = j >> 7;
            int ch  = j & 127;
            #pragma unroll
            for (int r = 0; r < 4; r++) {
                pv[((size_t)(n0 + kg * 4 + r) * 128 + ch) * 6 + seg] = f2b(accq[q][r] + bias);
            }
        }
    }
}

// ---------------------------------------------------------------- readout
__global__ __launch_bounds__(128) void out_mlp(
    const float* __restrict__ g,
    const float* __restrict__ w1, const float* __restrict__ b1,
    const float* __restrict__ w2, const float* __restrict__ b2,
    float* __restrict__ out)
{
    __shared__ float gl[D];
    __shared__ float red[2];
    int j = threadIdx.x;
    int gr = blockIdx.x;
    gl[j] = g[gr * D + j];
    __syncthreads();
    float acc = b1[j];
    for (int k = 0; k < D; k++) acc += gl[k] * w1[k * D + j];
    float h = silu_f(acc) * w2[j];
    #pragma unroll
    for (int off = 32; off >= 1; off >>= 1) h += __shfl_down(h, off);
    if ((j & 63) == 0) red[j >> 6] = h;
    __syncthreads();
    if (j == 0) out[gr] = red[0] + red[1] + b2[0];
}

// ================================================================ launch
extern "C" void kernel_launch(void* const* d_in, const int* in_sizes, int n_in,
                              void* d_out, int out_size, void* d_ws, size_t ws_size,
                              hipStream_t stream)
{
    const int*   edge_src   = (const int*)  d_in[0];
    const int*   edge_dst   = (const int*)  d_in[1];
    const float* edge_vec   = (const float*)d_in[2];
    const int*   atom_types = (const int*)  d_in[3];
    const int*   node_gi    = (const int*)  d_in[4];
    const float* embedding  = (const float*)d_in[5];
    const float* phi_w1     = (const float*)d_in[6];
    const float* phi_b1     = (const float*)d_in[7];
    const float* phi_w2     = (const float*)d_in[8];
    const float* phi_b2     = (const float*)d_in[9];
    const float* filt_w     = (const float*)d_in[10];
    const float* filt_b     = (const float*)d_in[11];
    const float* upd_w1     = (const float*)d_in[12];
    const float* upd_b1     = (const float*)d_in[13];
    const float* upd_w2     = (const float*)d_in[14];
    const float* upd_b2     = (const float*)d_in[15];
    const float* U_w        = (const float*)d_in[16];
    const float* V_w        = (const float*)d_in[17];
    const float* out_w1     = (const float*)d_in[18];
    const float* out_b1     = (const float*)d_in[19];
    const float* out_w2     = (const float*)d_in[20];
    const float* out_b2     = (const float*)d_in[21];

    float* ws = (float*)d_ws;
    size_t o = 0;
    float* s_a   = ws + o; o += (size_t)NN * D;
    float* s_b   = ws + o; o += (size_t)NN * D;
    float* v_a   = ws + o; o += (size_t)NN * 3 * D;
    float* v_b   = ws + o; o += (size_t)NN * 3 * D;
    float* pv_f  = ws + o; o += (size_t)NN * 384;             // pv: [n][128][6] bf16
    float* rbf_f = ws + o; o += (size_t)NE * RBF_ROW;         // fp32, CSR order
    float* geo   = ws + o; o += (size_t)NE * 4;               // CSR order
    float* g     = ws + o; o += (size_t)NG * D;
    float* w1t_f = ws + o; o += (size_t)D * D;                // phi w1 hi+lo
    float* w2t_f = ws + o; o += (size_t)D3 * D;               // phi w2 hi+lo
    float* uwt_f = ws + o; o += (size_t)D * D;                // Uw^T hi+lo
    float* vwt_f = ws + o; o += (size_t)D * D;                // Vw^T hi+lo
    float* u1t_f = ws + o; o += (size_t)2 * D * D;            // upd_w1^T hi+lo
    float* u2t_f = ws + o; o += (size_t)D3 * D;               // upd_w2^T hi+lo
    float* ptab_f= ws + o; o += (size_t)10 * D;               // round-0 phi table
    int* deg     = (int*)(ws + o); o += NN;
    int* offs    = (int*)(ws + o); o += NN + 1;
    int* cursor  = (int*)(ws + o); o += NN;
    int* perm    = (int*)(ws + o); o += NN;
    int* bpos    = (int*)(ws + o); o += 64;
    int* src_csr = (int*)(ws + o); o += NE;
    int* styp_csr= (int*)(ws + o); o += NE;

    ushort* pv    = (ushort*)pv_f;
    ushort* w1th  = (ushort*)w1t_f;
    ushort* w1tl  = w1th + (size_t)D * D;
    ushort* w2th  = (ushort*)w2t_f;
    ushort* w2tl  = w2th + (size_t)D3 * D;
    ushort* uwt   = (ushort*)uwt_f;
    ushort* vwt   = (ushort*)vwt_f;
    ushort* u1t   = (ushort*)u1t_f;
    ushort* u2t   = (ushort*)u2t_f;
    uint*   ptab  = (uint*)ptab_f;

    mega_init<<<512, 256, 0, stream>>>(g, deg, edge_dst, phi_w1, phi_w2,
                                       w1th, w1tl, w2th, w2tl,
                                       U_w, V_w, upd_w1, upd_w2,
                                       uwt, vwt, u1t, u2t);
    csr_count<<<(NE + 255) / 256, 256, 0, stream>>>(edge_dst, deg);
    scan_all<<<1, 1024, 0, stream>>>(deg, offs, cursor, bpos);
    geom_scatter<<<(NE + 255) / 256, 256, 0, stream>>>(edge_vec, edge_dst, edge_src,
                                                       atom_types, cursor,
                                                       rbf_f, (float4*)geo,
                                                       src_csr, styp_csr,
                                                       deg, bpos, perm);
    phi10<<<10, 128, 0, stream>>>(embedding, phi_w1, phi_b1, phi_w2, phi_b2, ptab);

    // round 0 (v = 0 specialization)
    node_gather_r0<<<NN / 4, 512, 0, stream>>>(offs, perm, styp_csr,
                                               atom_types, embedding, ptab,
                                               rbf_f, (const float4*)geo,
                                               filt_w, filt_b, s_b, v_b);
    node_vupd_mfma<true><<<NN / 16, 512, 0, stream>>>(s_b, v_b, pv, node_gi, g,
                                                      uwt, vwt, u1t, u2t,
                                                      upd_b1, upd_b2,
                                                      w1th, w1tl, phi_b1,
                                                      w2th, w2tl, phi_b2);
    // round 1
    node_gather<<<NN / 4, 512, 0, stream>>>(offs, perm, src_csr, pv,
                                            s_b, v_b, rbf_f,
                                            (const float4*)geo, filt_w, filt_b,
                                            s_a, v_a);
    node_vupd_mfma<false><<<NN / 16, 512, 0, stream>>>(s_a, v_a, pv, node_gi, g,
                                                       uwt, vwt, u1t, u2t,
                                                       upd_b1, upd_b2,
                                                       w1th, w1tl, phi_b1,
                                                       w2th, w2tl, phi_b2);

    out_mlp<<<NG, 128, 0, stream>>>(g, out_w1, out_b1, out_w2, out_b2, (float*)d_out);
}